// Round 8
// baseline (618.557 us; speedup 1.0000x reference)
//
#include <hip/hip_runtime.h>
#include <hip/hip_bf16.h>

// ---------------------------------------------------------------------------
// PE table (1024x512 fp32) + zero gamma (fused)
// ---------------------------------------------------------------------------
__global__ __launch_bounds__(256) void pe_k(float* __restrict__ PE,
                                            float* __restrict__ gamma)
{
    int idx = blockIdx.x * 256 + threadIdx.x;      // < 524288
    int d = idx & 511, s = idx >> 9;
    float expo = (float)(d & ~1) * (1.0f / 512.0f);
    float ang = (float)s * exp2f(-expo * 13.287712379549449f); // 10000^-expo
    PE[idx] = (d & 1) ? cosf(ang) : sinf(ang);
    if (idx < 128) gamma[idx] = 0.f;
}

// ---------------------------------------------------------------------------
// q0x_k: stage X0 = emb[tok0] + PE_row0 (all 32 b in LDS), compute
//   q0[b, h*128+f] = X0[b].Wq[h][:,f] + bq.  Grid 8 (64-col tiles).
// Weight read once grid-wide.
// ---------------------------------------------------------------------------
__global__ __launch_bounds__(256) void q0x_k(
    const int* __restrict__ inp, const float* __restrict__ emb,
    const float* __restrict__ Wp, const float* __restrict__ bp,
    float* __restrict__ X0, float* __restrict__ q0)
{
    __shared__ int toks[32];
    __shared__ float xs[32 * 512];
    int t = threadIdx.x, jt = blockIdx.x;
    if (t < 32) toks[t] = inp[t * 1024];
    __syncthreads();
#pragma unroll
    for (int i = 0; i < 16; i++) {
        int idx = t + i * 256;             // < 4096 float4
        int row = idx >> 7, c4 = idx & 127;
        float4 e4 = *(const float4*)&emb[(long)toks[row] * 512 + c4 * 4];
        float4 v = make_float4(e4.x, e4.y + 1.f, e4.z, e4.w + 1.f); // PE row 0
        *(float4*)&xs[row * 512 + c4 * 4] = v;
        if (jt == 0) *(float4*)&X0[row * 512 + c4 * 4] = v;
    }
    __syncthreads();
    int lane = t & 63, rowg = t >> 6;
    int h = jt >> 1, fl = (jt & 1) * 64 + lane;    // fl < 128
    const float* wq = Wp + (long)h * 196608 + fl;
    float acc[8] = {};
#pragma unroll 4
    for (int d = 0; d < 512; d++) {
        float w = wq[(long)d * 384];
#pragma unroll
        for (int rr = 0; rr < 8; rr++)
            acc[rr] += xs[(rowg * 8 + rr) * 512 + d] * w;
    }
    float bq = bp[h * 384 + fl];
#pragma unroll
    for (int rr = 0; rr < 8; rr++)
        q0[(rowg * 8 + rr) * 512 + h * 128 + fl] = acc[rr] + bq;
}

// ---------------------------------------------------------------------------
// r_k: r[b,h,d] = sum_f q0[b,h,f]*Wk[h,d,f]; also rT[d][bh] and
//   alpha[b,h] = q0[b,h,:].bk[h].  Grid (4 h, 8 dt).  Wk read once.
// ---------------------------------------------------------------------------
__global__ __launch_bounds__(256) void r_k(
    const float* __restrict__ q0, const float* __restrict__ Wp,
    const float* __restrict__ bp, float* __restrict__ r,
    float* __restrict__ rT, float* __restrict__ alpha)
{
    __shared__ float q0s[32 * 128];    // 16 KB
    __shared__ float Ws[128 * 65];     // 33 KB, [f][dl] padded
    int h = blockIdx.x, dt = blockIdx.y, t = threadIdx.x;
#pragma unroll
    for (int i = 0; i < 4; i++) {
        int idx = t + i * 256;             // < 1024 float4
        int row = idx >> 5, c4 = idx & 31;
        *(float4*)&q0s[row * 128 + c4 * 4] =
            *(const float4*)&q0[row * 512 + h * 128 + c4 * 4];
    }
#pragma unroll
    for (int i = 0; i < 8; i++) {
        int idx = t + i * 256;             // < 2048 float4
        int dl = idx >> 5, c4 = idx & 31;
        float4 w4 = *(const float4*)&Wp[(long)h * 196608
                                        + (long)(dt * 64 + dl) * 384 + 128 + c4 * 4];
        Ws[(c4 * 4 + 0) * 65 + dl] = w4.x;
        Ws[(c4 * 4 + 1) * 65 + dl] = w4.y;
        Ws[(c4 * 4 + 2) * 65 + dl] = w4.z;
        Ws[(c4 * 4 + 3) * 65 + dl] = w4.w;
    }
    __syncthreads();
    if (dt == 0 && t < 32) {
        float a = 0.f;
        for (int f = 0; f < 128; f++)
            a += q0s[t * 128 + f] * bp[h * 384 + 128 + f];
        alpha[t * 4 + h] = a;
    }
    int dl = t & 63, rowg = t >> 6;
    float acc[8] = {};
#pragma unroll 4
    for (int f = 0; f < 128; f++) {
        float w = Ws[f * 65 + dl];
#pragma unroll
        for (int rr = 0; rr < 8; rr++)
            acc[rr] += q0s[(rowg * 8 + rr) * 128 + f] * w;
    }
    int d = dt * 64 + dl;
#pragma unroll
    for (int rr = 0; rr < 8; rr++) {
        int b = rowg * 8 + rr;
        r[(b * 4 + h) * 512 + d] = acc[rr];
        rT[d * 128 + b * 4 + h] = acc[rr];
    }
}

// ---------------------------------------------------------------------------
// Generic fp32 tiled GEMM (round-0, proven).  C = op(A)@B.
// ---------------------------------------------------------------------------
template<bool TA, int ACT>
__global__ __launch_bounds__(256) void gemm_f32(
    const float* __restrict__ A, const float* __restrict__ Bm,
    const float* __restrict__ bias, float* __restrict__ C,
    int M, int N, int K, int lda, int ldb, int ldc, float alpha,
    long aOffB, long aOffH, long bOffB, long bOffH, long cOffB, long cOffH,
    int subH)
{
    constexpr int BM = 64, BN = 64, BK = 16;
    __shared__ float As[BK][BM + 1];
    __shared__ float Bs[BK][BN + 1];
    int tid = threadIdx.x;
    int bm = blockIdx.y * BM, bn = blockIdx.x * BN;
    int tm = (tid >> 4) << 2;
    int tn = (tid & 15) << 2;
    float acc[4][4] = {};
    for (int k0 = 0; k0 < K; k0 += BK) {
#pragma unroll
        for (int t = 0; t < 4; t++) {
            int i = tid + t * 256;
            if (TA) {
                int m = i & 63, kk = i >> 6;
                int gm = bm + m;
                As[kk][m] = (gm < M) ? A[(long)(k0 + kk) * lda + gm] : 0.f;
            } else {
                int m = i >> 4, kk = i & 15;
                int gm = bm + m;
                As[kk][m] = (gm < M) ? A[(long)gm * lda + (k0 + kk)] : 0.f;
            }
            int n = i & 63, kk2 = i >> 6;
            int gn = bn + n;
            Bs[kk2][n] = (gn < N) ? Bm[(long)(k0 + kk2) * ldb + gn] : 0.f;
        }
        __syncthreads();
#pragma unroll
        for (int kk = 0; kk < BK; kk++) {
            float a[4], bb[4];
#pragma unroll
            for (int i = 0; i < 4; i++) a[i] = As[kk][tm + i];
#pragma unroll
            for (int j = 0; j < 4; j++) bb[j] = Bs[kk][tn + j];
#pragma unroll
            for (int i = 0; i < 4; i++)
#pragma unroll
                for (int j = 0; j < 4; j++)
                    acc[i][j] += a[i] * bb[j];
        }
        __syncthreads();
    }
#pragma unroll
    for (int i = 0; i < 4; i++) {
        int gm = bm + tm + i;
        if (gm >= M) continue;
#pragma unroll
        for (int j = 0; j < 4; j++) {
            int gn = bn + tn + j;
            if (gn >= N) continue;
            C[(long)gm * ldc + gn] = alpha * acc[i][j];
        }
    }
}

// ---------------------------------------------------------------------------
// xu_k: fused emb-gather -> u -> t' emb-part partials. Grid (32 b, 16 sg),
// 64 s per block (2 tiles of 32). u = emb[tok].r + PEr[s] + alpha.
//   Tpp[(b*16+sg)][h][d] = sum_s emb[tok,d]*u[s,h];  U[s][bh]; gamma atomic.
// ---------------------------------------------------------------------------
__global__ __launch_bounds__(256) void xu_k(
    const int* __restrict__ inp, const float* __restrict__ emb,
    const float* __restrict__ r, const float* __restrict__ PEr,
    const float* __restrict__ alpha, float* __restrict__ Tpp,
    float* __restrict__ U, float* __restrict__ gamma)
{
    __shared__ float xs[32 * 516];     // 66 KB
    __shared__ float rs[4 * 520];      // 8.3 KB (pad 520: h-rows on distinct banks)
    __shared__ float us[128];
    __shared__ int  toks[32];
    int b = blockIdx.x, sg = blockIdx.y, t = threadIdx.x;
#pragma unroll
    for (int i = 0; i < 2; i++) {
        int idx = t + i * 256;             // < 512 float4
        int h = idx >> 7, k4 = idx & 127;
        *(float4*)&rs[h * 520 + k4 * 4] =
            *(const float4*)&r[(b * 4 + h) * 512 + k4 * 4];
    }
    float4 al = *(const float4*)&alpha[b * 4];
    float accT[4][2] = {};
    float gacc = 0.f;
    for (int it = 0; it < 2; it++) {
        int s0 = (sg * 2 + it) * 32;
        __syncthreads();
        if (t < 32) toks[t] = inp[b * 1024 + s0 + t];
        __syncthreads();
#pragma unroll
        for (int i = 0; i < 16; i++) {
            int idx = t + i * 256;         // < 4096 float4
            int row = idx >> 7, c4 = idx & 127;
            *(float4*)&xs[row * 516 + c4 * 4] =
                *(const float4*)&emb[(long)toks[row] * 512 + c4 * 4];
        }
        __syncthreads();
        {
            int s = t >> 3, h = (t >> 1) & 3, half = t & 1;
            const float* xrow = xs + s * 516 + half * 256;
            const float* rrow = rs + h * 520 + half * 256;
            float acc = 0.f;
#pragma unroll 8
            for (int k = 0; k < 64; k++) {
                float4 xv = *(const float4*)&xrow[k * 4];
                float4 rv = *(const float4*)&rrow[k * 4];
                acc += xv.x * rv.x + xv.y * rv.y + xv.z * rv.z + xv.w * rv.w;
            }
            acc += __shfl_xor(acc, 1);
            if (half == 0) {
                float alh = (h < 2) ? ((h == 0) ? al.x : al.y)
                                    : ((h == 2) ? al.z : al.w);
                us[s * 4 + h] = acc + PEr[(s0 + s) * 128 + b * 4 + h] + alh;
            }
        }
        __syncthreads();
        if (t < 128) {
            int sl = t >> 2, hh = t & 3;
            U[(s0 + sl) * 128 + b * 4 + hh] = us[t];
        }
        if (t < 4) {
#pragma unroll
            for (int s = 0; s < 32; s++) gacc += us[s * 4 + t];
        }
#pragma unroll 4
        for (int s = 0; s < 32; s++) {
            float x0 = xs[s * 516 + t];
            float x1 = xs[s * 516 + 256 + t];
#pragma unroll
            for (int h = 0; h < 4; h++) {
                float uv = us[s * 4 + h];
                accT[h][0] += uv * x0;
                accT[h][1] += uv * x1;
            }
        }
    }
    long base = (long)(b * 16 + sg) * 4;
#pragma unroll
    for (int h = 0; h < 4; h++) {
        Tpp[(base + h) * 512 + t] = accT[h][0];
        Tpp[(base + h) * 512 + 256 + t] = accT[h][1];
    }
    if (t < 4) atomicAdd(&gamma[b * 4 + t], gacc);
}

// ---------------------------------------------------------------------------
// att1_k: c0[b,h*128+e] = scale*(t'[b,h,:].Wv[h][:,e] + gamma*bv), where
//   t' = sum_sg Tpp + PEtUT.  Grid (4 h, 2 et); Wv read once grid-wide.
// ---------------------------------------------------------------------------
__global__ __launch_bounds__(256) void att1_k(
    const float* __restrict__ Tpp, const float* __restrict__ PEtUT,
    const float* __restrict__ gamma, const float* __restrict__ Wp,
    const float* __restrict__ bp, float* __restrict__ C0)
{
    __shared__ float tps[32 * 512];    // 64 KB
    int h = blockIdx.x, et = blockIdx.y, t = threadIdx.x;
#pragma unroll 2
    for (int i = 0; i < 64; i++) {
        int idx = t + i * 256;             // b*512+d
        int b = idx >> 9, d = idx & 511;
        float v = PEtUT[(b * 4 + h) * 512 + d];
#pragma unroll
        for (int sg = 0; sg < 16; sg++)
            v += Tpp[((long)((b * 16 + sg) * 4 + h)) * 512 + d];
        tps[idx] = v;
    }
    __syncthreads();
    int lane = t & 63, rowg = t >> 6;
    int e = et * 64 + lane;
    const float* wv = Wp + (long)h * 196608 + 256 + e;
    float acc[8] = {};
#pragma unroll 4
    for (int d = 0; d < 512; d++) {
        float w = wv[(long)d * 384];
#pragma unroll
        for (int rr = 0; rr < 8; rr++)
            acc[rr] += tps[(rowg * 8 + rr) * 512 + d] * w;
    }
    float gb = bp[h * 384 + 256 + e];
#pragma unroll
    for (int rr = 0; rr < 8; rr++) {
        int b = rowg * 8 + rr;
        C0[b * 512 + h * 128 + e] = 0.03125f * (acc[rr] + gamma[b * 4 + h] * gb);
    }
}

// ---------------------------------------------------------------------------
// att2_k: ATT0 = C0 @ Wo + bo.  Grid 8; Wo read once grid-wide.
// ---------------------------------------------------------------------------
__global__ __launch_bounds__(256) void att2_k(
    const float* __restrict__ C0, const float* __restrict__ Wo,
    const float* __restrict__ bo, float* __restrict__ ATT0)
{
    __shared__ float c0s[32 * 512];
    int jt = blockIdx.x, t = threadIdx.x;
#pragma unroll 2
    for (int i = 0; i < 64; i++) {
        int idx = t + i * 256;
        c0s[idx] = C0[idx];
    }
    __syncthreads();
    int lane = t & 63, rowg = t >> 6;
    int j = jt * 64 + lane;
    float acc[8] = {};
#pragma unroll 4
    for (int d = 0; d < 512; d++) {
        float w = Wo[(long)d * 512 + j];
#pragma unroll
        for (int rr = 0; rr < 8; rr++)
            acc[rr] += c0s[(rowg * 8 + rr) * 512 + d] * w;
    }
    float bj = bo[j];
#pragma unroll
    for (int rr = 0; rr < 8; rr++)
        ATT0[(rowg * 8 + rr) * 512 + j] = acc[rr] + bj;
}

// ---------------------------------------------------------------------------
// LN1: Y1 = LN(ATT0 + X0)*g + b.  Grid 32.
// ---------------------------------------------------------------------------
__global__ __launch_bounds__(256) void ln_rows_k(
    const float* __restrict__ in, const float* __restrict__ res,
    const float* __restrict__ g, const float* __restrict__ bta,
    float* __restrict__ out)
{
    int b = blockIdx.x, t = threadIdx.x;
    float a0 = in[b * 512 + t] + res[b * 512 + t];
    float a1 = in[b * 512 + t + 256] + res[b * 512 + t + 256];
    __shared__ float sd[8];
    float s = a0 + a1;
#pragma unroll
    for (int off = 32; off; off >>= 1) s += __shfl_down(s, off);
    if ((t & 63) == 0) sd[t >> 6] = s;
    __syncthreads();
    float mean = (sd[0] + sd[1] + sd[2] + sd[3]) * (1.0f / 512.0f);
    float d0 = a0 - mean, d1 = a1 - mean;
    float v = d0 * d0 + d1 * d1;
#pragma unroll
    for (int off = 32; off; off >>= 1) v += __shfl_down(v, off);
    if ((t & 63) == 0) sd[4 + (t >> 6)] = v;
    __syncthreads();
    float var = (sd[4] + sd[5] + sd[6] + sd[7]) * (1.0f / 512.0f);
    float rstd = rsqrtf(var + 0.001f);
    out[b * 512 + t] = d0 * rstd * g[t] + bta[t];
    out[b * 512 + t + 256] = d1 * rstd * g[t + 256] + bta[t + 256];
}

// ---------------------------------------------------------------------------
// FFN1 partials: Hp1[ks][32][2048].  Grid (32 jt, 4 ks).
// ---------------------------------------------------------------------------
__global__ __launch_bounds__(256) void ffn1_k(
    const float* __restrict__ Y1, const float* __restrict__ W1,
    float* __restrict__ Hp1)
{
    __shared__ float at[32][128];
    int jt = blockIdx.x, ks = blockIdx.y, t = threadIdx.x;
#pragma unroll
    for (int i = 0; i < 4; i++) {
        int idx = t + i * 256;
        int row = idx >> 5, f4 = idx & 31;
        ((float4*)at)[idx] = ((const float4*)(Y1 + (long)row * 512 + ks * 128))[f4];
    }
    __syncthreads();
    int j = jt * 64 + (t & 63), rg = t >> 6;
    float acc[8] = {};
    const float* wp = W1 + (long)(ks * 128) * 2048 + j;
#pragma unroll 4
    for (int k = 0; k < 128; k++) {
        float wv = wp[(long)k * 2048];
#pragma unroll
        for (int rr = 0; rr < 8; rr++)
            acc[rr] += at[rg * 8 + rr][k] * wv;
    }
#pragma unroll
    for (int rr = 0; rr < 8; rr++)
        Hp1[((long)(ks * 32 + rg * 8 + rr)) * 2048 + j] = acc[rr];
}

// ---------------------------------------------------------------------------
// FFN2 partials, fused relu(sum Hp1 + b1).  Grid (8 jt, 16 ks).
// ---------------------------------------------------------------------------
__global__ __launch_bounds__(256) void ffn2_k(
    const float* __restrict__ Hp1, const float* __restrict__ b1,
    const float* __restrict__ W2, float* __restrict__ Hp2)
{
    __shared__ float at[32][128];
    int jt = blockIdx.x, ks = blockIdx.y, t = threadIdx.x;
#pragma unroll
    for (int i = 0; i < 4; i++) {
        int idx = t + i * 256;
        int row = idx >> 5, f4 = idx & 31;
        int col4 = ks * 32 + f4;
        float4 v = ((const float4*)b1)[col4];
#pragma unroll
        for (int p = 0; p < 4; p++) {
            float4 pv = ((const float4*)Hp1)[(long)p * 16384 + (long)row * 512 + col4];
            v.x += pv.x; v.y += pv.y; v.z += pv.z; v.w += pv.w;
        }
        v.x = fmaxf(v.x, 0.f); v.y = fmaxf(v.y, 0.f);
        v.z = fmaxf(v.z, 0.f); v.w = fmaxf(v.w, 0.f);
        ((float4*)at)[idx] = v;
    }
    __syncthreads();
    int j = jt * 64 + (t & 63), rg = t >> 6;
    float acc[8] = {};
    const float* wp = W2 + (long)(ks * 128) * 512 + j;
#pragma unroll 4
    for (int k = 0; k < 128; k++) {
        float wv = wp[(long)k * 512];
#pragma unroll
        for (int rr = 0; rr < 8; rr++)
            acc[rr] += at[rg * 8 + rr][k] * wv;
    }
#pragma unroll
    for (int rr = 0; rr < 8; rr++)
        Hp2[((long)(ks * 32 + rg * 8 + rr)) * 512 + j] = acc[rr];
}

// ---------------------------------------------------------------------------
// X2 = LN(sum_ks Hp2 + b2 + Y1).  Grid 32.
// ---------------------------------------------------------------------------
__global__ __launch_bounds__(256) void ln2_k(
    const float* __restrict__ Hp2, const float* __restrict__ b2,
    const float* __restrict__ Y1, const float* __restrict__ g,
    const float* __restrict__ bta, float* __restrict__ X2)
{
    __shared__ float sd[8];
    int b = blockIdx.x, t = threadIdx.x;
    float a[2];
#pragma unroll
    for (int rep = 0; rep < 2; rep++) {
        int j = t + rep * 256;
        float v = b2[j] + Y1[b * 512 + j];
#pragma unroll
        for (int ks = 0; ks < 16; ks++)
            v += Hp2[((long)(ks * 32 + b)) * 512 + j];
        a[rep] = v;
    }
    float s = a[0] + a[1];
#pragma unroll
    for (int off = 32; off; off >>= 1) s += __shfl_down(s, off);
    if ((t & 63) == 0) sd[t >> 6] = s;
    __syncthreads();
    float mean = (sd[0] + sd[1] + sd[2] + sd[3]) * (1.0f / 512.0f);
    float d0 = a[0] - mean, d1 = a[1] - mean;
    float v2 = d0 * d0 + d1 * d1;
#pragma unroll
    for (int off = 32; off; off >>= 1) v2 += __shfl_down(v2, off);
    if ((t & 63) == 0) sd[4 + (t >> 6)] = v2;
    __syncthreads();
    float var = (sd[4] + sd[5] + sd[6] + sd[7]) * (1.0f / 512.0f);
    float rstd = rsqrtf(var + 0.001f);
    X2[b * 512 + t] = d0 * rstd * g[t] + bta[t];
    X2[b * 512 + t + 256] = d1 * rstd * g[t + 256] + bta[t + 256];
}

// ---------------------------------------------------------------------------
// head_k: Pl[b][jt] = sum_{j in tile} relu(X2[b].Wh[:,j]+bh[j])*Wf[j]
// Grid 8; Wh read once grid-wide.
// ---------------------------------------------------------------------------
__global__ __launch_bounds__(256) void head_k(
    const float* __restrict__ X2, const float* __restrict__ Wh,
    const float* __restrict__ bh, const float* __restrict__ Wf,
    float* __restrict__ Pl)
{
    __shared__ float xs[32 * 512];
    int jt = blockIdx.x, t = threadIdx.x;
#pragma unroll 2
    for (int i = 0; i < 64; i++) {
        int idx = t + i * 256;
        xs[idx] = X2[idx];
    }
    __syncthreads();
    int lane = t & 63, rowg = t >> 6;
    int j = jt * 64 + lane;
    float acc[8] = {};
#pragma unroll 4
    for (int d = 0; d < 512; d++) {
        float w = Wh[(long)d * 512 + j];
#pragma unroll
        for (int rr = 0; rr < 8; rr++)
            acc[rr] += xs[(rowg * 8 + rr) * 512 + d] * w;
    }
    float bj = bh[j], wf = Wf[j];
#pragma unroll
    for (int rr = 0; rr < 8; rr++) {
        float p = fmaxf(acc[rr] + bj, 0.f) * wf;
#pragma unroll
        for (int off = 32; off; off >>= 1) p += __shfl_down(p, off);
        if (lane == 0) Pl[(rowg * 8 + rr) * 8 + jt] = p;
    }
}

__global__ __launch_bounds__(64) void final_k(
    const float* __restrict__ Pl, const float* __restrict__ bf,
    float* __restrict__ out)
{
    int t = threadIdx.x;
    if (t < 32) {
        float logit = bf[0];
#pragma unroll
        for (int jt = 0; jt < 8; jt++) logit += Pl[t * 8 + jt];
        out[t] = logit;
        out[32 + t] = 1.f / (1.f + expf(-logit));
    }
}

// ---------------------------------------------------------------------------
extern "C" void kernel_launch(void* const* d_in, const int* in_sizes, int n_in,
                              void* d_out, int out_size, void* d_ws, size_t ws_size,
                              hipStream_t stream)
{
    const int*   inputs = (const int*)  d_in[0];
    const float* emb    = (const float*)d_in[1];
    const float* Wp     = (const float*)d_in[2];
    const float* bp     = (const float*)d_in[3];
    const float* Wo     = (const float*)d_in[4];
    const float* bo     = (const float*)d_in[5];
    const float* ln1_g  = (const float*)d_in[6];
    const float* ln1_b  = (const float*)d_in[7];
    const float* W1     = (const float*)d_in[8];
    const float* b1     = (const float*)d_in[9];
    const float* W2     = (const float*)d_in[10];
    const float* b2     = (const float*)d_in[11];
    const float* ln2_g  = (const float*)d_in[12];
    const float* ln2_b  = (const float*)d_in[13];
    const float* Wh     = (const float*)d_in[14];
    const float* bh     = (const float*)d_in[15];
    const float* Wf     = (const float*)d_in[16];
    const float* bf     = (const float*)d_in[17];
    float* out = (float*)d_out;

    char* p = (char*)d_ws;
    float* PE    = (float*)p;  p += 2097152;    // (1024,512)
    float* X0    = (float*)p;  p += 65536;      // (32,512)
    float* q0    = (float*)p;  p += 65536;      // (32,512)
    float* r     = (float*)p;  p += 262144;     // (128,512)
    float* rT    = (float*)p;  p += 262144;     // (512,128)
    float* alpha = (float*)p;  p += 1024;       // (128)+pad
    float* gamma = (float*)p;  p += 1024;       // (128) [zeroed in pe_k]
    float* PEr   = (float*)p;  p += 524288;     // (1024,128)
    float* U     = (float*)p;  p += 524288;     // (1024,128)
    float* PEtUT = (float*)p;  p += 262144;     // (128,512)
    float* Tpp   = (float*)p;  p += 4194304;    // (32,16,4,512)
    float* C0    = (float*)p;  p += 65536;      // (32,512)
    float* ATT0  = (float*)p;  p += 65536;      // (32,512)
    float* Y1    = (float*)p;  p += 65536;      // (32,512)
    float* Hp1   = (float*)p;  p += 1048576;    // (4,32,2048)
    float* Hp2   = (float*)p;  p += 1048576;    // (16,32,512)
    float* X2    = (float*)p;  p += 65536;      // (32,512)
    float* Pl    = (float*)p;  p += 1024;       // (32,8)

    pe_k<<<2048, 256, 0, stream>>>(PE, gamma);
    q0x_k<<<8, 256, 0, stream>>>(inputs, emb, Wp, bp, X0, q0);
    r_k<<<dim3(4, 8), 256, 0, stream>>>(q0, Wp, bp, r, rT, alpha);
    // PEr[s][bh] = PE @ rT   (M=1024, N=128, K=512)
    gemm_f32<false, 0><<<dim3(2, 16), 256, 0, stream>>>(
        PE, rT, nullptr, PEr, 1024, 128, 512, 512, 128, 128, 1.0f,
        0, 0, 0, 0, 0, 0, 1);
    xu_k<<<dim3(32, 16), 256, 0, stream>>>(inputs, emb, r, PEr, alpha,
                                           Tpp, U, gamma);
    // PEtUT[bh][d] = U^T @ PE  (TA: A=U[k=s][m=bh], B=PE[k=s][n=d])
    gemm_f32<true, 0><<<dim3(8, 2), 256, 0, stream>>>(
        U, PE, nullptr, PEtUT, 128, 512, 1024, 128, 512, 512, 1.0f,
        0, 0, 0, 0, 0, 0, 1);
    att1_k<<<dim3(4, 2), 256, 0, stream>>>(Tpp, PEtUT, gamma, Wp, bp, C0);
    att2_k<<<8, 256, 0, stream>>>(C0, Wo, bo, ATT0);
    ln_rows_k<<<32, 256, 0, stream>>>(ATT0, X0, ln1_g, ln1_b, Y1);
    ffn1_k<<<dim3(32, 4), 256, 0, stream>>>(Y1, W1, Hp1);
    ffn2_k<<<dim3(8, 16), 256, 0, stream>>>(Hp1, b1, W2, Hp2);
    ln2_k<<<32, 256, 0, stream>>>(Hp2, b2, Y1, ln2_g, ln2_b, X2);
    head_k<<<8, 256, 0, stream>>>(X2, Wh, bh, Wf, Pl);
    final_k<<<1, 64, 0, stream>>>(Pl, bf, out);
}

// Round 9
// 287.996 us; speedup vs baseline: 2.1478x; 2.1478x over previous
//
#include <hip/hip_runtime.h>
#include <hip/hip_bf16.h>

// ---------------------------------------------------------------------------
// qr_k: per (b,h): X0row = emb[tok[b,0]] + PE_row0 (sin0=0 even d, cos0=1 odd d)
//   q0[f] = X0row . Wq[h][:,f] + bq[f];  alpha[b,h] = q0 . bk[h]
//   r[(b*4+h)][d] = sum_f q0[f] * Wk[h][d][f]
// Grid (32 b, 4 h).
// ---------------------------------------------------------------------------
__global__ __launch_bounds__(256) void qr_k(
    const int* __restrict__ inp, const float* __restrict__ emb,
    const float* __restrict__ Wp, const float* __restrict__ bp,
    float* __restrict__ X0, float* __restrict__ r, float* __restrict__ alpha)
{
    __shared__ float xs[512];
    __shared__ float red[256];
    __shared__ float q0s[128];
    int b = blockIdx.x, h = blockIdx.y, t = threadIdx.x;
    int tok0 = inp[b * 1024];
#pragma unroll
    for (int rep = 0; rep < 2; rep++) {
        int d = t + rep * 256;
        float v = emb[(long)tok0 * 512 + d] + ((d & 1) ? 1.0f : 0.0f);
        xs[d] = v;
        if (h == 0) X0[b * 512 + d] = v;
    }
    __syncthreads();

    int f = t & 127, dh = t >> 7;
    const float* wq = Wp + (long)h * 196608 + f;
    float acc = 0.f;
#pragma unroll 8
    for (int d = dh * 256; d < dh * 256 + 256; d++)
        acc += xs[d] * wq[(long)d * 384];
    red[t] = acc;
    __syncthreads();
    if (t < 128) q0s[t] = red[t] + red[t + 128] + bp[h * 384 + t];
    __syncthreads();
    if (t < 128) red[t] = q0s[t] * bp[h * 384 + 128 + t];
    __syncthreads();
    for (int w = 64; w >= 1; w >>= 1) {
        if (t < w) red[t] += red[t + w];
        __syncthreads();
    }
    if (t == 0) alpha[b * 4 + h] = red[0];

    const float4* q4 = (const float4*)q0s;
#pragma unroll
    for (int rep = 0; rep < 2; rep++) {
        int d = t + rep * 256;
        const float4* wr = (const float4*)(Wp + ((long)(h * 512 + d)) * 384 + 128);
        float a2 = 0.f;
#pragma unroll 8
        for (int f4 = 0; f4 < 32; f4++) {
            float4 w = wr[f4], qq = q4[f4];
            a2 += w.x * qq.x + w.y * qq.y + w.z * qq.z + w.w * qq.w;
        }
        r[((long)(b * 4 + h)) * 512 + d] = a2;
    }
}

// ---------------------------------------------------------------------------
// xu_k: fused x-gather (PE inline) -> u -> t' partials. Grid (32 b, 32 sc).
//   Phase 1: stage x[s][d] = emb[tok] + PE(s,d) into LDS (stride 516).
//   Phase 2: u[s,h] = x[s].r[b,h] + alpha.
//   Phase 3: Tpp[(b*32+sc)][h][d] = sum_s x[s][d]*u[s,h]; Gp partial of gamma.
// ---------------------------------------------------------------------------
__global__ __launch_bounds__(256) void xu_k(
    const int* __restrict__ inp, const float* __restrict__ emb,
    const float* __restrict__ r, const float* __restrict__ alpha,
    float* __restrict__ Tpp, float* __restrict__ Gp)
{
    __shared__ float xs[32 * 516];     // 66 KB
    __shared__ float rs[2048];         // r[b] 4x512
    __shared__ float us[128];          // u[s][h]
    __shared__ int  toks[32];
    int b = blockIdx.x, sc = blockIdx.y, t = threadIdx.x;
    int wave = t >> 6, lane = t & 63;

    if (t < 32) toks[t] = inp[b * 1024 + sc * 32 + t];
#pragma unroll
    for (int i = 0; i < 2; i++)
        ((float4*)rs)[t + i * 256] = ((const float4*)(r + (long)b * 2048))[t + i * 256];

    // per-thread PE frequencies for d = lane*8 + {0..7} (pairs share freq)
    float w4[4];
#pragma unroll
    for (int j = 0; j < 4; j++) {
        float expo = (float)(lane * 8 + j * 2) * (1.0f / 512.0f);
        w4[j] = exp2f(-expo * 13.287712379549449f);   // 10000^-expo
    }
    __syncthreads();

    // Phase 1: each wave stages 8 rows; x = emb[tok] + PE(s,d) computed inline
#pragma unroll
    for (int i = 0; i < 8; i++) {
        int row = wave * 8 + i;
        float s = (float)(sc * 32 + row);
        int tok = toks[row];
        const float4* e = (const float4*)&emb[(long)tok * 512 + lane * 8];
        float4 e0 = e[0], e1 = e[1];
        float sv[4], cv[4];
#pragma unroll
        for (int j = 0; j < 4; j++) {
            float ang = s * w4[j];
            sv[j] = sinf(ang);
            cv[j] = cosf(ang);
        }
        *(float4*)&xs[row * 516 + lane * 8] =
            make_float4(e0.x + sv[0], e0.y + cv[0], e0.z + sv[1], e0.w + cv[1]);
        *(float4*)&xs[row * 516 + lane * 8 + 4] =
            make_float4(e1.x + sv[2], e1.y + cv[2], e1.z + sv[3], e1.w + cv[3]);
    }
    __syncthreads();

    // Phase 2: u[s,h] = x[s].r[h] + alpha[h]   (thread = (s,h,half))
    {
        int s = t >> 3, h = (t >> 1) & 3, half = t & 1;
        const float* xrow = xs + s * 516 + half * 256;
        const float* rrow = rs + h * 512 + half * 256;
        float acc = 0.f;
#pragma unroll 8
        for (int k = 0; k < 64; k++) {
            float4 xv = *(const float4*)&xrow[k * 4];
            float4 rv = *(const float4*)&rrow[k * 4];
            acc += xv.x * rv.x + xv.y * rv.y + xv.z * rv.z + xv.w * rv.w;
        }
        acc += __shfl_xor(acc, 1);
        if (half == 0) us[s * 4 + h] = acc + alpha[b * 4 + h];
    }
    __syncthreads();

    // gamma partial (no atomics): Gp[(b*32+sc)*4+h] = sum_s u[s,h]
    if (t < 4) {
        float gacc = 0.f;
#pragma unroll
        for (int s = 0; s < 32; s++) gacc += us[s * 4 + t];
        Gp[(b * 32 + sc) * 4 + t] = gacc;
    }

    // Phase 3: t' partials, d = t and t+256
    float accT[4][2] = {};
#pragma unroll 4
    for (int s = 0; s < 32; s++) {
        float x0 = xs[s * 516 + t];
        float x1 = xs[s * 516 + 256 + t];
#pragma unroll
        for (int h = 0; h < 4; h++) {
            float uv = us[s * 4 + h];
            accT[h][0] += uv * x0;
            accT[h][1] += uv * x1;
        }
    }
    long base = (long)(b * 32 + sc) * 2048;
#pragma unroll
    for (int h = 0; h < 4; h++) {
        Tpp[base + h * 512 + t] = accT[h][0];
        Tpp[base + h * 512 + 256 + t] = accT[h][1];
    }
}

// ---------------------------------------------------------------------------
// att1_k: c0[b, h*128+e] = scale*(sum_d t'[h][d] Wv[h][d][e] + gamma[h] bv[h][e])
// Grid (32 b, 8 jt). Sums 32 sc-partials of t' and gamma on load.
// ---------------------------------------------------------------------------
__global__ __launch_bounds__(256) void att1_k(
    const float* __restrict__ Tpp, const float* __restrict__ Gp,
    const float* __restrict__ Wp, const float* __restrict__ bp,
    float* __restrict__ C0)
{
    __shared__ float tps[512];
    __shared__ float red[256];
    int b = blockIdx.x, jt = blockIdx.y, t = threadIdx.x;
    int h = jt >> 1, e0 = (jt & 1) * 64;
#pragma unroll
    for (int i = 0; i < 2; i++) {
        int d = t + i * 256;
        float v = 0.f;
#pragma unroll 8
        for (int sc = 0; sc < 32; sc++)
            v += Tpp[(long)b * 65536 + sc * 2048 + h * 512 + d];
        tps[d] = v;
    }
    __syncthreads();
    int e = e0 + (t & 63), rg = t >> 6;
    const float* wv = Wp + (long)h * 196608 + 256 + e;
    float acc = 0.f;
#pragma unroll 8
    for (int d = rg * 128; d < rg * 128 + 128; d++)
        acc += tps[d] * wv[(long)d * 384];
    red[t] = acc;
    __syncthreads();
    if (t < 64) {
        float gam = 0.f;
#pragma unroll
        for (int sc = 0; sc < 32; sc++) gam += Gp[(b * 32 + sc) * 4 + h];
        float sum = red[t] + red[t + 64] + red[t + 128] + red[t + 192];
        float c = 0.03125f * (sum + gam * bp[h * 384 + 256 + e0 + t]);
        C0[b * 512 + h * 128 + e0 + t] = c;
    }
}

// ---------------------------------------------------------------------------
// att2ln_k: ATT0 = C0 @ Wo + bo; Y1 = LN(ATT0 + X0).  Grid 32 (block per b).
// ---------------------------------------------------------------------------
__global__ __launch_bounds__(256) void att2ln_k(
    const float* __restrict__ C0, const float* __restrict__ Wo,
    const float* __restrict__ bo, const float* __restrict__ X0,
    const float* __restrict__ g, const float* __restrict__ bta,
    float* __restrict__ Y1)
{
    __shared__ float c0s[512];
    __shared__ float sd[8];
    int b = blockIdx.x, t = threadIdx.x;
    c0s[t] = C0[b * 512 + t];
    c0s[t + 256] = C0[b * 512 + t + 256];
    __syncthreads();
    float a[2];
#pragma unroll
    for (int rep = 0; rep < 2; rep++) {
        int j = t + rep * 256;
        float acc = bo[j];
#pragma unroll 8
        for (int d = 0; d < 512; d++)
            acc += c0s[d] * Wo[(long)d * 512 + j];
        a[rep] = acc + X0[b * 512 + j];
    }
    float s = a[0] + a[1];
#pragma unroll
    for (int off = 32; off; off >>= 1) s += __shfl_down(s, off);
    if ((t & 63) == 0) sd[t >> 6] = s;
    __syncthreads();
    float mean = (sd[0] + sd[1] + sd[2] + sd[3]) * (1.0f / 512.0f);
    float d0 = a[0] - mean, d1 = a[1] - mean;
    float v = d0 * d0 + d1 * d1;
#pragma unroll
    for (int off = 32; off; off >>= 1) v += __shfl_down(v, off);
    if ((t & 63) == 0) sd[4 + (t >> 6)] = v;
    __syncthreads();
    float var = (sd[4] + sd[5] + sd[6] + sd[7]) * (1.0f / 512.0f);
    float rstd = rsqrtf(var + 0.001f);
    Y1[b * 512 + t] = d0 * rstd * g[t] + bta[t];
    Y1[b * 512 + t + 256] = d1 * rstd * g[t + 256] + bta[t + 256];
}

// ---------------------------------------------------------------------------
// FFN1 partials: Hp1[ks][32][2048] = Y1[:, kchunk] @ W1[kchunk, :]
// Grid (32 jt, 4 ks).
// ---------------------------------------------------------------------------
__global__ __launch_bounds__(256) void ffn1_k(
    const float* __restrict__ Y1, const float* __restrict__ W1,
    float* __restrict__ Hp1)
{
    __shared__ float at[32][128];
    int jt = blockIdx.x, ks = blockIdx.y, t = threadIdx.x;
#pragma unroll
    for (int i = 0; i < 4; i++) {
        int idx = t + i * 256;
        int row = idx >> 5, f4 = idx & 31;
        ((float4*)at)[idx] = ((const float4*)(Y1 + (long)row * 512 + ks * 128))[f4];
    }
    __syncthreads();
    int j = jt * 64 + (t & 63), rg = t >> 6;
    float acc[8] = {};
    const float* wp = W1 + (long)(ks * 128) * 2048 + j;
#pragma unroll 4
    for (int k = 0; k < 128; k++) {
        float wv = wp[(long)k * 2048];
#pragma unroll
        for (int rr = 0; rr < 8; rr++)
            acc[rr] += at[rg * 8 + rr][k] * wv;
    }
#pragma unroll
    for (int rr = 0; rr < 8; rr++)
        Hp1[((long)(ks * 32 + rg * 8 + rr)) * 2048 + j] = acc[rr];
}

// ---------------------------------------------------------------------------
// FFN2 partials, fused H1 = relu(sum_ks Hp1 + b1) at staging.
// Hp2[ks][32][512] = H1[:, kchunk] @ W2[kchunk, :].  Grid (8 jt, 16 ks).
// ---------------------------------------------------------------------------
__global__ __launch_bounds__(256) void ffn2_k(
    const float* __restrict__ Hp1, const float* __restrict__ b1,
    const float* __restrict__ W2, float* __restrict__ Hp2)
{
    __shared__ float at[32][128];
    int jt = blockIdx.x, ks = blockIdx.y, t = threadIdx.x;
#pragma unroll
    for (int i = 0; i < 4; i++) {
        int idx = t + i * 256;
        int row = idx >> 5, f4 = idx & 31;
        int col4 = ks * 32 + f4;
        float4 v = ((const float4*)b1)[col4];
#pragma unroll
        for (int p = 0; p < 4; p++) {
            float4 pv = ((const float4*)Hp1)[(long)p * 16384 + (long)row * 512 + col4];
            v.x += pv.x; v.y += pv.y; v.z += pv.z; v.w += pv.w;
        }
        v.x = fmaxf(v.x, 0.f); v.y = fmaxf(v.y, 0.f);
        v.z = fmaxf(v.z, 0.f); v.w = fmaxf(v.w, 0.f);
        ((float4*)at)[idx] = v;
    }
    __syncthreads();
    int j = jt * 64 + (t & 63), rg = t >> 6;
    float acc[8] = {};
    const float* wp = W2 + (long)(ks * 128) * 512 + j;
#pragma unroll 4
    for (int k = 0; k < 128; k++) {
        float wv = wp[(long)k * 512];
#pragma unroll
        for (int rr = 0; rr < 8; rr++)
            acc[rr] += at[rg * 8 + rr][k] * wv;
    }
#pragma unroll
    for (int rr = 0; rr < 8; rr++)
        Hp2[((long)(ks * 32 + rg * 8 + rr)) * 512 + j] = acc[rr];
}

// ---------------------------------------------------------------------------
// headln_k: X2 = LN(sum_ks Hp2 + b2 + Y1); hid = relu(X2.Wh+bh);
//   logit = hid.Wf + bf; out = [logit, sigmoid].  Grid 32 (block per b).
// ---------------------------------------------------------------------------
__global__ __launch_bounds__(256) void headln_k(
    const float* __restrict__ Hp2, const float* __restrict__ b2,
    const float* __restrict__ Y1, const float* __restrict__ g,
    const float* __restrict__ bta, const float* __restrict__ Wh,
    const float* __restrict__ bh, const float* __restrict__ Wf,
    const float* __restrict__ bf, float* __restrict__ out)
{
    __shared__ float xs[512];
    __shared__ float sd[8];
    int b = blockIdx.x, t = threadIdx.x;
    float a[2];
#pragma unroll
    for (int rep = 0; rep < 2; rep++) {
        int j = t + rep * 256;
        float v = b2[j] + Y1[b * 512 + j];
#pragma unroll
        for (int ks = 0; ks < 16; ks++)
            v += Hp2[((long)(ks * 32 + b)) * 512 + j];
        a[rep] = v;
    }
    float s = a[0] + a[1];
#pragma unroll
    for (int off = 32; off; off >>= 1) s += __shfl_down(s, off);
    if ((t & 63) == 0) sd[t >> 6] = s;
    __syncthreads();
    float mean = (sd[0] + sd[1] + sd[2] + sd[3]) * (1.0f / 512.0f);
    float d0 = a[0] - mean, d1 = a[1] - mean;
    float v2 = d0 * d0 + d1 * d1;
#pragma unroll
    for (int off = 32; off; off >>= 1) v2 += __shfl_down(v2, off);
    if ((t & 63) == 0) sd[4 + (t >> 6)] = v2;
    __syncthreads();
    float var = (sd[4] + sd[5] + sd[6] + sd[7]) * (1.0f / 512.0f);
    float rstd = rsqrtf(var + 0.001f);
    xs[t] = d0 * rstd * g[t] + bta[t];
    xs[t + 256] = d1 * rstd * g[t + 256] + bta[t + 256];
    __syncthreads();

    float p = 0.f;
#pragma unroll
    for (int rep = 0; rep < 2; rep++) {
        int j = t + rep * 256;
        float acc = bh[j];
#pragma unroll 8
        for (int d = 0; d < 512; d++) acc += xs[d] * Wh[(long)d * 512 + j];
        p += fmaxf(acc, 0.f) * Wf[j];
    }
#pragma unroll
    for (int off = 32; off; off >>= 1) p += __shfl_down(p, off);
    if ((t & 63) == 0) sd[t >> 6] = p;
    __syncthreads();
    if (t == 0) {
        float logit = sd[0] + sd[1] + sd[2] + sd[3] + bf[0];
        out[b] = logit;
        out[32 + b] = 1.f / (1.f + expf(-logit));
    }
}

// ---------------------------------------------------------------------------
extern "C" void kernel_launch(void* const* d_in, const int* in_sizes, int n_in,
                              void* d_out, int out_size, void* d_ws, size_t ws_size,
                              hipStream_t stream)
{
    const int*   inputs = (const int*)  d_in[0];
    const float* emb    = (const float*)d_in[1];
    const float* Wp     = (const float*)d_in[2];
    const float* bp     = (const float*)d_in[3];
    const float* Wo     = (const float*)d_in[4];
    const float* bo     = (const float*)d_in[5];
    const float* ln1_g  = (const float*)d_in[6];
    const float* ln1_b  = (const float*)d_in[7];
    const float* W1     = (const float*)d_in[8];
    const float* b1     = (const float*)d_in[9];
    const float* W2     = (const float*)d_in[10];
    const float* b2     = (const float*)d_in[11];
    const float* ln2_g  = (const float*)d_in[12];
    const float* ln2_b  = (const float*)d_in[13];
    const float* Wh     = (const float*)d_in[14];
    const float* bh     = (const float*)d_in[15];
    const float* Wf     = (const float*)d_in[16];
    const float* bf     = (const float*)d_in[17];
    float* out = (float*)d_out;

    char* p = (char*)d_ws;
    float* X0    = (float*)p;  p += 65536;      // (32,512)
    float* r     = (float*)p;  p += 262144;     // (128,512)
    float* alpha = (float*)p;  p += 1024;       // (128)+pad
    float* Gp    = (float*)p;  p += 16384;      // (32,32,4)
    float* Tpp   = (float*)p;  p += 8388608;    // (32,32,4,512)
    float* C0    = (float*)p;  p += 65536;      // (32,512)
    float* Y1    = (float*)p;  p += 65536;      // (32,512)
    float* Hp1   = (float*)p;  p += 1048576;    // (4,32,2048)
    float* Hp2   = (float*)p;  p += 1048576;    // (16,32,512)

    qr_k<<<dim3(32, 4), 256, 0, stream>>>(inputs, emb, Wp, bp, X0, r, alpha);
    xu_k<<<dim3(32, 32), 256, 0, stream>>>(inputs, emb, r, alpha, Tpp, Gp);
    att1_k<<<dim3(32, 8), 256, 0, stream>>>(Tpp, Gp, Wp, bp, C0);
    att2ln_k<<<32, 256, 0, stream>>>(C0, Wo, bo, X0, ln1_g, ln1_b, Y1);
    ffn1_k<<<dim3(32, 4), 256, 0, stream>>>(Y1, W1, Hp1);
    ffn2_k<<<dim3(8, 16), 256, 0, stream>>>(Hp1, b1, W2, Hp2);
    headln_k<<<32, 256, 0, stream>>>(Hp2, b2, Y1, ln2_g, ln2_b,
                                     Wh, bh, Wf, bf, out);
}

// Round 10
// 211.314 us; speedup vs baseline: 2.9272x; 1.3629x over previous
//
#include <hip/hip_runtime.h>
#include <hip/hip_bf16.h>

// ---------------------------------------------------------------------------
// qr_k: per (b,h): X0row = emb[tok[b,0]] + PE_row0 (sin0=0 even d, cos0=1 odd)
//   q0[f] = X0row . Wq[h][:,f] + bq[f];  alpha[b,h] = q0 . bk[h]
//   r[(b*4+h)][d] = sum_f q0[f] * Wk[h][d][f]
// Grid (32 b, 4 h).
// ---------------------------------------------------------------------------
__global__ __launch_bounds__(256) void qr_k(
    const int* __restrict__ inp, const float* __restrict__ emb,
    const float* __restrict__ Wp, const float* __restrict__ bp,
    float* __restrict__ X0, float* __restrict__ r, float* __restrict__ alpha)
{
    __shared__ float xs[512];
    __shared__ float red[256];
    __shared__ float q0s[128];
    int b = blockIdx.x, h = blockIdx.y, t = threadIdx.x;
    int tok0 = inp[b * 1024];
#pragma unroll
    for (int rep = 0; rep < 2; rep++) {
        int d = t + rep * 256;
        float v = emb[(long)tok0 * 512 + d] + ((d & 1) ? 1.0f : 0.0f);
        xs[d] = v;
        if (h == 0) X0[b * 512 + d] = v;
    }
    __syncthreads();

    int f = t & 127, dh = t >> 7;
    const float* wq = Wp + (long)h * 196608 + f;
    float acc = 0.f;
#pragma unroll 8
    for (int d = dh * 256; d < dh * 256 + 256; d++)
        acc += xs[d] * wq[(long)d * 384];
    red[t] = acc;
    __syncthreads();
    if (t < 128) q0s[t] = red[t] + red[t + 128] + bp[h * 384 + t];
    __syncthreads();
    if (t < 128) red[t] = q0s[t] * bp[h * 384 + 128 + t];
    __syncthreads();
    for (int w = 64; w >= 1; w >>= 1) {
        if (t < w) red[t] += red[t + w];
        __syncthreads();
    }
    if (t == 0) alpha[b * 4 + h] = red[0];

    const float4* q4 = (const float4*)q0s;
#pragma unroll
    for (int rep = 0; rep < 2; rep++) {
        int d = t + rep * 256;
        const float4* wr = (const float4*)(Wp + ((long)(h * 512 + d)) * 384 + 128);
        float a2 = 0.f;
#pragma unroll 8
        for (int f4 = 0; f4 < 32; f4++) {
            float4 w = wr[f4], qq = q4[f4];
            a2 += w.x * qq.x + w.y * qq.y + w.z * qq.z + w.w * qq.w;
        }
        r[((long)(b * 4 + h)) * 512 + d] = a2;
    }
}

// ---------------------------------------------------------------------------
// xu_k: fused x-gather (PE inline) -> u -> t' partials. Grid (32 b, 32 sc).
// ---------------------------------------------------------------------------
__global__ __launch_bounds__(256) void xu_k(
    const int* __restrict__ inp, const float* __restrict__ emb,
    const float* __restrict__ r, const float* __restrict__ alpha,
    float* __restrict__ Tpp, float* __restrict__ Gp)
{
    __shared__ float xs[32 * 516];     // 66 KB
    __shared__ float rs[2048];         // r[b] 4x512
    __shared__ float us[128];          // u[s][h]
    __shared__ int  toks[32];
    int b = blockIdx.x, sc = blockIdx.y, t = threadIdx.x;
    int wave = t >> 6, lane = t & 63;

    if (t < 32) toks[t] = inp[b * 1024 + sc * 32 + t];
#pragma unroll
    for (int i = 0; i < 2; i++)
        ((float4*)rs)[t + i * 256] = ((const float4*)(r + (long)b * 2048))[t + i * 256];

    float w4[4];
#pragma unroll
    for (int j = 0; j < 4; j++) {
        float expo = (float)(lane * 8 + j * 2) * (1.0f / 512.0f);
        w4[j] = exp2f(-expo * 13.287712379549449f);   // 10000^-expo
    }
    __syncthreads();

#pragma unroll
    for (int i = 0; i < 8; i++) {
        int row = wave * 8 + i;
        float s = (float)(sc * 32 + row);
        int tok = toks[row];
        const float4* e = (const float4*)&emb[(long)tok * 512 + lane * 8];
        float4 e0 = e[0], e1 = e[1];
        float sv[4], cv[4];
#pragma unroll
        for (int j = 0; j < 4; j++) {
            float ang = s * w4[j];
            sv[j] = sinf(ang);
            cv[j] = cosf(ang);
        }
        *(float4*)&xs[row * 516 + lane * 8] =
            make_float4(e0.x + sv[0], e0.y + cv[0], e0.z + sv[1], e0.w + cv[1]);
        *(float4*)&xs[row * 516 + lane * 8 + 4] =
            make_float4(e1.x + sv[2], e1.y + cv[2], e1.z + sv[3], e1.w + cv[3]);
    }
    __syncthreads();

    {
        int s = t >> 3, h = (t >> 1) & 3, half = t & 1;
        const float* xrow = xs + s * 516 + half * 256;
        const float* rrow = rs + h * 512 + half * 256;
        float acc = 0.f;
#pragma unroll 8
        for (int k = 0; k < 64; k++) {
            float4 xv = *(const float4*)&xrow[k * 4];
            float4 rv = *(const float4*)&rrow[k * 4];
            acc += xv.x * rv.x + xv.y * rv.y + xv.z * rv.z + xv.w * rv.w;
        }
        acc += __shfl_xor(acc, 1);
        if (half == 0) us[s * 4 + h] = acc + alpha[b * 4 + h];
    }
    __syncthreads();

    if (t < 4) {
        float gacc = 0.f;
#pragma unroll
        for (int s = 0; s < 32; s++) gacc += us[s * 4 + t];
        Gp[(b * 32 + sc) * 4 + t] = gacc;
    }

    float accT[4][2] = {};
#pragma unroll 4
    for (int s = 0; s < 32; s++) {
        float x0 = xs[s * 516 + t];
        float x1 = xs[s * 516 + 256 + t];
#pragma unroll
        for (int h = 0; h < 4; h++) {
            float uv = us[s * 4 + h];
            accT[h][0] += uv * x0;
            accT[h][1] += uv * x1;
        }
    }
    long base = (long)(b * 32 + sc) * 2048;
#pragma unroll
    for (int h = 0; h < 4; h++) {
        Tpp[base + h * 512 + t] = accT[h][0];
        Tpp[base + h * 512 + 256 + t] = accT[h][1];
    }
}

// ---------------------------------------------------------------------------
// att1_k: c0[b,h*128+e] = scale*(sum_d t'[h][d] Wv[h][d][e] + gamma[h] bv)
// Grid (32 b, 8 jt). Sums 32 sc-partials of t' and gamma on load.
// ---------------------------------------------------------------------------
__global__ __launch_bounds__(256) void att1_k(
    const float* __restrict__ Tpp, const float* __restrict__ Gp,
    const float* __restrict__ Wp, const float* __restrict__ bp,
    float* __restrict__ C0)
{
    __shared__ float tps[512];
    __shared__ float red[256];
    int b = blockIdx.x, jt = blockIdx.y, t = threadIdx.x;
    int h = jt >> 1, e0 = (jt & 1) * 64;
#pragma unroll
    for (int i = 0; i < 2; i++) {
        int d = t + i * 256;
        float v = 0.f;
#pragma unroll 8
        for (int sc = 0; sc < 32; sc++)
            v += Tpp[(long)b * 65536 + sc * 2048 + h * 512 + d];
        tps[d] = v;
    }
    __syncthreads();
    int e = e0 + (t & 63), rg = t >> 6;
    const float* wv = Wp + (long)h * 196608 + 256 + e;
    float acc = 0.f;
#pragma unroll 8
    for (int d = rg * 128; d < rg * 128 + 128; d++)
        acc += tps[d] * wv[(long)d * 384];
    red[t] = acc;
    __syncthreads();
    if (t < 64) {
        float gam = 0.f;
#pragma unroll
        for (int sc = 0; sc < 32; sc++) gam += Gp[(b * 32 + sc) * 4 + h];
        float sum = red[t] + red[t + 64] + red[t + 128] + red[t + 192];
        float c = 0.03125f * (sum + gam * bp[h * 384 + 256 + e0 + t]);
        C0[b * 512 + h * 128 + e0 + t] = c;
    }
}

// ---------------------------------------------------------------------------
// att2_k: ATT0 = c0 @ Wo + bo.  Grid (32 b, 8 jt).
// ---------------------------------------------------------------------------
__global__ __launch_bounds__(256) void att2_k(
    const float* __restrict__ C0, const float* __restrict__ Wo,
    const float* __restrict__ bo, float* __restrict__ ATT0)
{
    __shared__ float c0s[512];
    __shared__ float red[256];
    int b = blockIdx.x, jt = blockIdx.y, t = threadIdx.x;
    c0s[t] = C0[b * 512 + t];
    c0s[t + 256] = C0[b * 512 + t + 256];
    __syncthreads();
    int j = jt * 64 + (t & 63), rg = t >> 6;
    float acc = 0.f;
#pragma unroll 8
    for (int d = rg * 128; d < rg * 128 + 128; d++)
        acc += c0s[d] * Wo[(long)d * 512 + j];
    red[t] = acc;
    __syncthreads();
    if (t < 64) {
        int jj = jt * 64 + t;
        ATT0[b * 512 + jj] = red[t] + red[t + 64] + red[t + 128] + red[t + 192] + bo[jj];
    }
}

// ---------------------------------------------------------------------------
// LN1: Y1 = LN(ATT0 + X0)*g + b.  Grid 32.
// ---------------------------------------------------------------------------
__global__ __launch_bounds__(256) void ln_rows_k(
    const float* __restrict__ in, const float* __restrict__ res,
    const float* __restrict__ g, const float* __restrict__ bta,
    float* __restrict__ out)
{
    int b = blockIdx.x, t = threadIdx.x;
    float a0 = in[b * 512 + t] + res[b * 512 + t];
    float a1 = in[b * 512 + t + 256] + res[b * 512 + t + 256];
    __shared__ float sd[8];
    float s = a0 + a1;
#pragma unroll
    for (int off = 32; off; off >>= 1) s += __shfl_down(s, off);
    if ((t & 63) == 0) sd[t >> 6] = s;
    __syncthreads();
    float mean = (sd[0] + sd[1] + sd[2] + sd[3]) * (1.0f / 512.0f);
    float d0 = a0 - mean, d1 = a1 - mean;
    float v = d0 * d0 + d1 * d1;
#pragma unroll
    for (int off = 32; off; off >>= 1) v += __shfl_down(v, off);
    if ((t & 63) == 0) sd[4 + (t >> 6)] = v;
    __syncthreads();
    float var = (sd[4] + sd[5] + sd[6] + sd[7]) * (1.0f / 512.0f);
    float rstd = rsqrtf(var + 0.001f);
    out[b * 512 + t] = d0 * rstd * g[t] + bta[t];
    out[b * 512 + t + 256] = d1 * rstd * g[t + 256] + bta[t + 256];
}

// ---------------------------------------------------------------------------
// FFN1 partials: Hp1[ks][32][2048] = Y1[:, kchunk] @ W1[kchunk, :]
// Grid (32 jt, 4 ks).
// ---------------------------------------------------------------------------
__global__ __launch_bounds__(256) void ffn1_k(
    const float* __restrict__ Y1, const float* __restrict__ W1,
    float* __restrict__ Hp1)
{
    __shared__ float at[32][128];
    int jt = blockIdx.x, ks = blockIdx.y, t = threadIdx.x;
#pragma unroll
    for (int i = 0; i < 4; i++) {
        int idx = t + i * 256;
        int row = idx >> 5, f4 = idx & 31;
        ((float4*)at)[idx] = ((const float4*)(Y1 + (long)row * 512 + ks * 128))[f4];
    }
    __syncthreads();
    int j = jt * 64 + (t & 63), rg = t >> 6;
    float acc[8] = {};
    const float* wp = W1 + (long)(ks * 128) * 2048 + j;
#pragma unroll 4
    for (int k = 0; k < 128; k++) {
        float wv = wp[(long)k * 2048];
#pragma unroll
        for (int rr = 0; rr < 8; rr++)
            acc[rr] += at[rg * 8 + rr][k] * wv;
    }
#pragma unroll
    for (int rr = 0; rr < 8; rr++)
        Hp1[((long)(ks * 32 + rg * 8 + rr)) * 2048 + j] = acc[rr];
}

// ---------------------------------------------------------------------------
// FFN2 partials, fused H1 = relu(sum_ks Hp1 + b1) at staging.
// Grid (8 jt, 16 ks).
// ---------------------------------------------------------------------------
__global__ __launch_bounds__(256) void ffn2_k(
    const float* __restrict__ Hp1, const float* __restrict__ b1,
    const float* __restrict__ W2, float* __restrict__ Hp2)
{
    __shared__ float at[32][128];
    int jt = blockIdx.x, ks = blockIdx.y, t = threadIdx.x;
#pragma unroll
    for (int i = 0; i < 4; i++) {
        int idx = t + i * 256;
        int row = idx >> 5, f4 = idx & 31;
        int col4 = ks * 32 + f4;
        float4 v = ((const float4*)b1)[col4];
#pragma unroll
        for (int p = 0; p < 4; p++) {
            float4 pv = ((const float4*)Hp1)[(long)p * 16384 + (long)row * 512 + col4];
            v.x += pv.x; v.y += pv.y; v.z += pv.z; v.w += pv.w;
        }
        v.x = fmaxf(v.x, 0.f); v.y = fmaxf(v.y, 0.f);
        v.z = fmaxf(v.z, 0.f); v.w = fmaxf(v.w, 0.f);
        ((float4*)at)[idx] = v;
    }
    __syncthreads();
    int j = jt * 64 + (t & 63), rg = t >> 6;
    float acc[8] = {};
    const float* wp = W2 + (long)(ks * 128) * 512 + j;
#pragma unroll 4
    for (int k = 0; k < 128; k++) {
        float wv = wp[(long)k * 512];
#pragma unroll
        for (int rr = 0; rr < 8; rr++)
            acc[rr] += at[rg * 8 + rr][k] * wv;
    }
#pragma unroll
    for (int rr = 0; rr < 8; rr++)
        Hp2[((long)(ks * 32 + rg * 8 + rr)) * 512 + j] = acc[rr];
}

// ---------------------------------------------------------------------------
// headp2_k: fused LN2 + head partials.  Grid (32 b, 8 jt).
//   X2row = LN(sum_ks Hp2 + b2 + Y1) (redundant per jt, L2-hot)
//   Pl[b][jt] = sum_{j in tile} relu(X2row.Wh[:,j]+bh[j])*Wf[j]
// ---------------------------------------------------------------------------
__global__ __launch_bounds__(256) void headp2_k(
    const float* __restrict__ Hp2, const float* __restrict__ b2,
    const float* __restrict__ Y1, const float* __restrict__ g,
    const float* __restrict__ bta, const float* __restrict__ Wh,
    const float* __restrict__ bh, const float* __restrict__ Wf,
    float* __restrict__ Pl)
{
    __shared__ float xs[512];
    __shared__ float red[256];
    __shared__ float sd[8];
    int b = blockIdx.x, jt = blockIdx.y, t = threadIdx.x;
    float a[2];
#pragma unroll
    for (int rep = 0; rep < 2; rep++) {
        int j = t + rep * 256;
        float v = b2[j] + Y1[b * 512 + j];
#pragma unroll
        for (int ks = 0; ks < 16; ks++)
            v += Hp2[((long)(ks * 32 + b)) * 512 + j];
        a[rep] = v;
    }
    float s = a[0] + a[1];
#pragma unroll
    for (int off = 32; off; off >>= 1) s += __shfl_down(s, off);
    if ((t & 63) == 0) sd[t >> 6] = s;
    __syncthreads();
    float mean = (sd[0] + sd[1] + sd[2] + sd[3]) * (1.0f / 512.0f);
    float d0 = a[0] - mean, d1 = a[1] - mean;
    float v2 = d0 * d0 + d1 * d1;
#pragma unroll
    for (int off = 32; off; off >>= 1) v2 += __shfl_down(v2, off);
    if ((t & 63) == 0) sd[4 + (t >> 6)] = v2;
    __syncthreads();
    float var = (sd[4] + sd[5] + sd[6] + sd[7]) * (1.0f / 512.0f);
    float rstd = rsqrtf(var + 0.001f);
    xs[t] = d0 * rstd * g[t] + bta[t];
    xs[t + 256] = d1 * rstd * g[t + 256] + bta[t + 256];
    __syncthreads();

    int j = jt * 64 + (t & 63), rg = t >> 6;
    const float* w = Wh + j;
    float acc = 0.f;
#pragma unroll 8
    for (int d = rg * 128; d < rg * 128 + 128; d++)
        acc += xs[d] * w[(long)d * 512];
    red[t] = acc;
    __syncthreads();
    if (t < 64) {
        int jj = jt * 64 + t;
        float hid = red[t] + red[t + 64] + red[t + 128] + red[t + 192] + bh[jj];
        hid = fmaxf(hid, 0.f);
        float p = hid * Wf[jj];
#pragma unroll
        for (int off = 32; off; off >>= 1) p += __shfl_down(p, off);
        if (t == 0) Pl[b * 8 + jt] = p;
    }
}

__global__ __launch_bounds__(64) void final_k(
    const float* __restrict__ Pl, const float* __restrict__ bf,
    float* __restrict__ out)
{
    int t = threadIdx.x;
    if (t < 32) {
        float logit = bf[0];
#pragma unroll
        for (int jt = 0; jt < 8; jt++) logit += Pl[t * 8 + jt];
        out[t] = logit;
        out[32 + t] = 1.f / (1.f + expf(-logit));
    }
}

// ---------------------------------------------------------------------------
extern "C" void kernel_launch(void* const* d_in, const int* in_sizes, int n_in,
                              void* d_out, int out_size, void* d_ws, size_t ws_size,
                              hipStream_t stream)
{
    const int*   inputs = (const int*)  d_in[0];
    const float* emb    = (const float*)d_in[1];
    const float* Wp     = (const float*)d_in[2];
    const float* bp     = (const float*)d_in[3];
    const float* Wo     = (const float*)d_in[4];
    const float* bo     = (const float*)d_in[5];
    const float* ln1_g  = (const float*)d_in[6];
    const float* ln1_b  = (const float*)d_in[7];
    const float* W1     = (const float*)d_in[8];
    const float* b1     = (const float*)d_in[9];
    const float* W2     = (const float*)d_in[10];
    const float* b2     = (const float*)d_in[11];
    const float* ln2_g  = (const float*)d_in[12];
    const float* ln2_b  = (const float*)d_in[13];
    const float* Wh     = (const float*)d_in[14];
    const float* bh     = (const float*)d_in[15];
    const float* Wf     = (const float*)d_in[16];
    const float* bf     = (const float*)d_in[17];
    float* out = (float*)d_out;

    char* p = (char*)d_ws;
    float* X0    = (float*)p;  p += 65536;      // (32,512)
    float* r     = (float*)p;  p += 262144;     // (128,512)
    float* alpha = (float*)p;  p += 1024;       // (128)+pad
    float* Gp    = (float*)p;  p += 16384;      // (32,32,4)
    float* Tpp   = (float*)p;  p += 8388608;    // (32,32,4,512)
    float* C0    = (float*)p;  p += 65536;      // (32,512)
    float* ATT0  = (float*)p;  p += 65536;      // (32,512)
    float* Y1    = (float*)p;  p += 65536;      // (32,512)
    float* Hp1   = (float*)p;  p += 1048576;    // (4,32,2048)
    float* Hp2   = (float*)p;  p += 1048576;    // (16,32,512)
    float* Pl    = (float*)p;  p += 1024;       // (32,8)

    qr_k<<<dim3(32, 4), 256, 0, stream>>>(inputs, emb, Wp, bp, X0, r, alpha);
    xu_k<<<dim3(32, 32), 256, 0, stream>>>(inputs, emb, r, alpha, Tpp, Gp);
    att1_k<<<dim3(32, 8), 256, 0, stream>>>(Tpp, Gp, Wp, bp, C0);
    att2_k<<<dim3(32, 8), 256, 0, stream>>>(C0, Wo, bo, ATT0);
    ln_rows_k<<<32, 256, 0, stream>>>(ATT0, X0, ln1_g, ln1_b, Y1);
    ffn1_k<<<dim3(32, 4), 256, 0, stream>>>(Y1, W1, Hp1);
    ffn2_k<<<dim3(8, 16), 256, 0, stream>>>(Hp1, b1, W2, Hp2);
    headp2_k<<<dim3(32, 8), 256, 0, stream>>>(Hp2, b2, Y1, ln2_g, ln2_b,
                                              Wh, bh, Wf, Pl);
    final_k<<<1, 64, 0, stream>>>(Pl, bf, out);
}

// Round 11
// 202.243 us; speedup vs baseline: 3.0585x; 1.0449x over previous
//
#include <hip/hip_runtime.h>
#include <hip/hip_bf16.h>

// ---------------------------------------------------------------------------
// qr_k: per (b,h): X0row = emb[tok[b,0]] + PE_row0 (sin0=0 even d, cos0=1 odd)
//   q0[f] = X0row . Wq[h][:,f] + bq[f];  alpha[b,h] = q0 . bk[h]
//   r[(b*4+h)][d] = sum_f q0[f] * Wk[h][d][f]
// Grid (32 b, 4 h).
// ---------------------------------------------------------------------------
__global__ __launch_bounds__(256) void qr_k(
    const int* __restrict__ inp, const float* __restrict__ emb,
    const float* __restrict__ Wp, const float* __restrict__ bp,
    float* __restrict__ X0, float* __restrict__ r, float* __restrict__ alpha)
{
    __shared__ float xs[512];
    __shared__ float red[256];
    __shared__ float q0s[128];
    int b = blockIdx.x, h = blockIdx.y, t = threadIdx.x;
    int tok0 = inp[b * 1024];
#pragma unroll
    for (int rep = 0; rep < 2; rep++) {
        int d = t + rep * 256;
        float v = emb[(long)tok0 * 512 + d] + ((d & 1) ? 1.0f : 0.0f);
        xs[d] = v;
        if (h == 0) X0[b * 512 + d] = v;
    }
    __syncthreads();

    int f = t & 127, dh = t >> 7;
    const float* wq = Wp + (long)h * 196608 + f;
    float acc = 0.f;
#pragma unroll 8
    for (int d = dh * 256; d < dh * 256 + 256; d++)
        acc += xs[d] * wq[(long)d * 384];
    red[t] = acc;
    __syncthreads();
    if (t < 128) q0s[t] = red[t] + red[t + 128] + bp[h * 384 + t];
    __syncthreads();
    if (t < 128) red[t] = q0s[t] * bp[h * 384 + 128 + t];
    __syncthreads();
    for (int w = 64; w >= 1; w >>= 1) {
        if (t < w) red[t] += red[t + w];
        __syncthreads();
    }
    if (t == 0) alpha[b * 4 + h] = red[0];

    const float4* q4 = (const float4*)q0s;
#pragma unroll
    for (int rep = 0; rep < 2; rep++) {
        int d = t + rep * 256;
        const float4* wr = (const float4*)(Wp + ((long)(h * 512 + d)) * 384 + 128);
        float a2 = 0.f;
#pragma unroll 8
        for (int f4 = 0; f4 < 32; f4++) {
            float4 w = wr[f4], qq = q4[f4];
            a2 += w.x * qq.x + w.y * qq.y + w.z * qq.z + w.w * qq.w;
        }
        r[((long)(b * 4 + h)) * 512 + d] = a2;
    }
}

// ---------------------------------------------------------------------------
// xu_k: fused x-gather (PE inline) -> u -> t' partials. Grid (32 b, 16 sg),
// 2 chunks of 32 s per block.
//   rs padded to stride 520 (520%32=8 -> h-rows on distinct bank groups;
//   2-way half-aliasing is free) — fixes the 16-way conflict of stride 512.
// ---------------------------------------------------------------------------
__global__ __launch_bounds__(256) void xu_k(
    const int* __restrict__ inp, const float* __restrict__ emb,
    const float* __restrict__ r, const float* __restrict__ alpha,
    float* __restrict__ Tpp, float* __restrict__ Gp)
{
    __shared__ float xs[32 * 516];     // 66 KB
    __shared__ float rs[4 * 520];      // 8.3 KB, padded stride
    __shared__ float us[128];          // u[s][h]
    __shared__ int  toks[32];
    int b = blockIdx.x, sg = blockIdx.y, t = threadIdx.x;
    int wave = t >> 6, lane = t & 63;

#pragma unroll
    for (int i = 0; i < 2; i++) {
        int idx = t + i * 256;             // < 512 float4-units
        int h = idx >> 7, k4 = idx & 127;
        *(float4*)&rs[h * 520 + k4 * 4] =
            *(const float4*)&r[((long)(b * 4 + h)) * 512 + k4 * 4];
    }

    float w4[4];
#pragma unroll
    for (int j = 0; j < 4; j++) {
        float expo = (float)(lane * 8 + j * 2) * (1.0f / 512.0f);
        w4[j] = exp2f(-expo * 13.287712379549449f);   // 10000^-expo
    }

    float accT[4][2] = {};
    float gacc = 0.f;
    for (int it = 0; it < 2; it++) {
        int s0 = (sg * 2 + it) * 32;
        __syncthreads();                    // protect xs/us from prev readers
        if (t < 32) toks[t] = inp[b * 1024 + s0 + t];
        __syncthreads();

        // Phase 1: each wave stages 8 rows; x = emb[tok] + PE(s,d) inline
#pragma unroll
        for (int i = 0; i < 8; i++) {
            int row = wave * 8 + i;
            float s = (float)(s0 + row);
            int tok = toks[row];
            const float4* e = (const float4*)&emb[(long)tok * 512 + lane * 8];
            float4 e0 = e[0], e1 = e[1];
            float sv[4], cv[4];
#pragma unroll
            for (int j = 0; j < 4; j++) {
                float ang = s * w4[j];
                sv[j] = sinf(ang);
                cv[j] = cosf(ang);
            }
            *(float4*)&xs[row * 516 + lane * 8] =
                make_float4(e0.x + sv[0], e0.y + cv[0], e0.z + sv[1], e0.w + cv[1]);
            *(float4*)&xs[row * 516 + lane * 8 + 4] =
                make_float4(e1.x + sv[2], e1.y + cv[2], e1.z + sv[3], e1.w + cv[3]);
        }
        __syncthreads();

        // Phase 2: u[s,h] = x[s].r[h] + alpha[h]   (thread = (s,h,half))
        {
            int s = t >> 3, h = (t >> 1) & 3, half = t & 1;
            const float* xrow = xs + s * 516 + half * 256;
            const float* rrow = rs + h * 520 + half * 256;
            float acc = 0.f;
#pragma unroll 8
            for (int k = 0; k < 64; k++) {
                float4 xv = *(const float4*)&xrow[k * 4];
                float4 rv = *(const float4*)&rrow[k * 4];
                acc += xv.x * rv.x + xv.y * rv.y + xv.z * rv.z + xv.w * rv.w;
            }
            acc += __shfl_xor(acc, 1);
            if (half == 0) us[s * 4 + h] = acc + alpha[b * 4 + h];
        }
        __syncthreads();

        // gamma partial
        if (t < 4) {
#pragma unroll
            for (int s = 0; s < 32; s++) gacc += us[s * 4 + t];
        }

        // Phase 3: t' partials, d = t and t+256
#pragma unroll 4
        for (int s = 0; s < 32; s++) {
            float x0 = xs[s * 516 + t];
            float x1 = xs[s * 516 + 256 + t];
#pragma unroll
            for (int h = 0; h < 4; h++) {
                float uv = us[s * 4 + h];
                accT[h][0] += uv * x0;
                accT[h][1] += uv * x1;
            }
        }
    }
    long base = (long)(b * 16 + sg) * 2048;
#pragma unroll
    for (int h = 0; h < 4; h++) {
        Tpp[base + h * 512 + t] = accT[h][0];
        Tpp[base + h * 512 + 256 + t] = accT[h][1];
    }
    if (t < 4) Gp[(b * 16 + sg) * 4 + t] = gacc;
}

// ---------------------------------------------------------------------------
// att1_k: c0[b,h*128+e] = scale*(sum_d t'[h][d] Wv[h][d][e] + gamma[h] bv)
// Grid (32 b, 8 jt). Sums 16 sg-partials of t' and gamma on load.
// ---------------------------------------------------------------------------
__global__ __launch_bounds__(256) void att1_k(
    const float* __restrict__ Tpp, const float* __restrict__ Gp,
    const float* __restrict__ Wp, const float* __restrict__ bp,
    float* __restrict__ C0)
{
    __shared__ float tps[512];
    __shared__ float red[256];
    int b = blockIdx.x, jt = blockIdx.y, t = threadIdx.x;
    int h = jt >> 1, e0 = (jt & 1) * 64;
#pragma unroll
    for (int i = 0; i < 2; i++) {
        int d = t + i * 256;
        float v = 0.f;
#pragma unroll 8
        for (int sg = 0; sg < 16; sg++)
            v += Tpp[(long)b * 32768 + sg * 2048 + h * 512 + d];
        tps[d] = v;
    }
    __syncthreads();
    int e = e0 + (t & 63), rg = t >> 6;
    const float* wv = Wp + (long)h * 196608 + 256 + e;
    float acc = 0.f;
#pragma unroll 8
    for (int d = rg * 128; d < rg * 128 + 128; d++)
        acc += tps[d] * wv[(long)d * 384];
    red[t] = acc;
    __syncthreads();
    if (t < 64) {
        float gam = 0.f;
#pragma unroll
        for (int sg = 0; sg < 16; sg++) gam += Gp[(b * 16 + sg) * 4 + h];
        float sum = red[t] + red[t + 64] + red[t + 128] + red[t + 192];
        float c = 0.03125f * (sum + gam * bp[h * 384 + 256 + e0 + t]);
        C0[b * 512 + h * 128 + e0 + t] = c;
    }
}

// ---------------------------------------------------------------------------
// att2_k: ATT0 = c0 @ Wo + bo.  Grid (32 b, 8 jt).
// ---------------------------------------------------------------------------
__global__ __launch_bounds__(256) void att2_k(
    const float* __restrict__ C0, const float* __restrict__ Wo,
    const float* __restrict__ bo, float* __restrict__ ATT0)
{
    __shared__ float c0s[512];
    __shared__ float red[256];
    int b = blockIdx.x, jt = blockIdx.y, t = threadIdx.x;
    c0s[t] = C0[b * 512 + t];
    c0s[t + 256] = C0[b * 512 + t + 256];
    __syncthreads();
    int j = jt * 64 + (t & 63), rg = t >> 6;
    float acc = 0.f;
#pragma unroll 8
    for (int d = rg * 128; d < rg * 128 + 128; d++)
        acc += c0s[d] * Wo[(long)d * 512 + j];
    red[t] = acc;
    __syncthreads();
    if (t < 64) {
        int jj = jt * 64 + t;
        ATT0[b * 512 + jj] = red[t] + red[t + 64] + red[t + 128] + red[t + 192] + bo[jj];
    }
}

// ---------------------------------------------------------------------------
// LN1: Y1 = LN(ATT0 + X0)*g + b.  Grid 32.
// ---------------------------------------------------------------------------
__global__ __launch_bounds__(256) void ln_rows_k(
    const float* __restrict__ in, const float* __restrict__ res,
    const float* __restrict__ g, const float* __restrict__ bta,
    float* __restrict__ out)
{
    int b = blockIdx.x, t = threadIdx.x;
    float a0 = in[b * 512 + t] + res[b * 512 + t];
    float a1 = in[b * 512 + t + 256] + res[b * 512 + t + 256];
    __shared__ float sd[8];
    float s = a0 + a1;
#pragma unroll
    for (int off = 32; off; off >>= 1) s += __shfl_down(s, off);
    if ((t & 63) == 0) sd[t >> 6] = s;
    __syncthreads();
    float mean = (sd[0] + sd[1] + sd[2] + sd[3]) * (1.0f / 512.0f);
    float d0 = a0 - mean, d1 = a1 - mean;
    float v = d0 * d0 + d1 * d1;
#pragma unroll
    for (int off = 32; off; off >>= 1) v += __shfl_down(v, off);
    if ((t & 63) == 0) sd[4 + (t >> 6)] = v;
    __syncthreads();
    float var = (sd[4] + sd[5] + sd[6] + sd[7]) * (1.0f / 512.0f);
    float rstd = rsqrtf(var + 0.001f);
    out[b * 512 + t] = d0 * rstd * g[t] + bta[t];
    out[b * 512 + t + 256] = d1 * rstd * g[t + 256] + bta[t + 256];
}

// ---------------------------------------------------------------------------
// FFN1 partials: Hp1[ks][32][2048] = Y1[:, kchunk] @ W1[kchunk, :]
// Grid (32 jt, 4 ks).
// ---------------------------------------------------------------------------
__global__ __launch_bounds__(256) void ffn1_k(
    const float* __restrict__ Y1, const float* __restrict__ W1,
    float* __restrict__ Hp1)
{
    __shared__ float at[32][128];
    int jt = blockIdx.x, ks = blockIdx.y, t = threadIdx.x;
#pragma unroll
    for (int i = 0; i < 4; i++) {
        int idx = t + i * 256;
        int row = idx >> 5, f4 = idx & 31;
        ((float4*)at)[idx] = ((const float4*)(Y1 + (long)row * 512 + ks * 128))[f4];
    }
    __syncthreads();
    int j = jt * 64 + (t & 63), rg = t >> 6;
    float acc[8] = {};
    const float* wp = W1 + (long)(ks * 128) * 2048 + j;
#pragma unroll 4
    for (int k = 0; k < 128; k++) {
        float wv = wp[(long)k * 2048];
#pragma unroll
        for (int rr = 0; rr < 8; rr++)
            acc[rr] += at[rg * 8 + rr][k] * wv;
    }
#pragma unroll
    for (int rr = 0; rr < 8; rr++)
        Hp1[((long)(ks * 32 + rg * 8 + rr)) * 2048 + j] = acc[rr];
}

// ---------------------------------------------------------------------------
// FFN2 partials, fused H1 = relu(sum_ks Hp1 + b1) at staging.
// Grid (8 jt, 16 ks).
// ---------------------------------------------------------------------------
__global__ __launch_bounds__(256) void ffn2_k(
    const float* __restrict__ Hp1, const float* __restrict__ b1,
    const float* __restrict__ W2, float* __restrict__ Hp2)
{
    __shared__ float at[32][128];
    int jt = blockIdx.x, ks = blockIdx.y, t = threadIdx.x;
#pragma unroll
    for (int i = 0; i < 4; i++) {
        int idx = t + i * 256;
        int row = idx >> 5, f4 = idx & 31;
        int col4 = ks * 32 + f4;
        float4 v = ((const float4*)b1)[col4];
#pragma unroll
        for (int p = 0; p < 4; p++) {
            float4 pv = ((const float4*)Hp1)[(long)p * 16384 + (long)row * 512 + col4];
            v.x += pv.x; v.y += pv.y; v.z += pv.z; v.w += pv.w;
        }
        v.x = fmaxf(v.x, 0.f); v.y = fmaxf(v.y, 0.f);
        v.z = fmaxf(v.z, 0.f); v.w = fmaxf(v.w, 0.f);
        ((float4*)at)[idx] = v;
    }
    __syncthreads();
    int j = jt * 64 + (t & 63), rg = t >> 6;
    float acc[8] = {};
    const float* wp = W2 + (long)(ks * 128) * 512 + j;
#pragma unroll 4
    for (int k = 0; k < 128; k++) {
        float wv = wp[(long)k * 512];
#pragma unroll
        for (int rr = 0; rr < 8; rr++)
            acc[rr] += at[rg * 8 + rr][k] * wv;
    }
#pragma unroll
    for (int rr = 0; rr < 8; rr++)
        Hp2[((long)(ks * 32 + rg * 8 + rr)) * 512 + j] = acc[rr];
}

// ---------------------------------------------------------------------------
// headp2_k: fused LN2 + head partials.  Grid (32 b, 8 jt).
// ---------------------------------------------------------------------------
__global__ __launch_bounds__(256) void headp2_k(
    const float* __restrict__ Hp2, const float* __restrict__ b2,
    const float* __restrict__ Y1, const float* __restrict__ g,
    const float* __restrict__ bta, const float* __restrict__ Wh,
    const float* __restrict__ bh, const float* __restrict__ Wf,
    float* __restrict__ Pl)
{
    __shared__ float xs[512];
    __shared__ float red[256];
    __shared__ float sd[8];
    int b = blockIdx.x, jt = blockIdx.y, t = threadIdx.x;
    float a[2];
#pragma unroll
    for (int rep = 0; rep < 2; rep++) {
        int j = t + rep * 256;
        float v = b2[j] + Y1[b * 512 + j];
#pragma unroll
        for (int ks = 0; ks < 16; ks++)
            v += Hp2[((long)(ks * 32 + b)) * 512 + j];
        a[rep] = v;
    }
    float s = a[0] + a[1];
#pragma unroll
    for (int off = 32; off; off >>= 1) s += __shfl_down(s, off);
    if ((t & 63) == 0) sd[t >> 6] = s;
    __syncthreads();
    float mean = (sd[0] + sd[1] + sd[2] + sd[3]) * (1.0f / 512.0f);
    float d0 = a[0] - mean, d1 = a[1] - mean;
    float v2 = d0 * d0 + d1 * d1;
#pragma unroll
    for (int off = 32; off; off >>= 1) v2 += __shfl_down(v2, off);
    if ((t & 63) == 0) sd[4 + (t >> 6)] = v2;
    __syncthreads();
    float var = (sd[4] + sd[5] + sd[6] + sd[7]) * (1.0f / 512.0f);
    float rstd = rsqrtf(var + 0.001f);
    xs[t] = d0 * rstd * g[t] + bta[t];
    xs[t + 256] = d1 * rstd * g[t + 256] + bta[t + 256];
    __syncthreads();

    int j = jt * 64 + (t & 63), rg = t >> 6;
    const float* w = Wh + j;
    float acc = 0.f;
#pragma unroll 8
    for (int d = rg * 128; d < rg * 128 + 128; d++)
        acc += xs[d] * w[(long)d * 512];
    red[t] = acc;
    __syncthreads();
    if (t < 64) {
        int jj = jt * 64 + t;
        float hid = red[t] + red[t + 64] + red[t + 128] + red[t + 192] + bh[jj];
        hid = fmaxf(hid, 0.f);
        float p = hid * Wf[jj];
#pragma unroll
        for (int off = 32; off; off >>= 1) p += __shfl_down(p, off);
        if (t == 0) Pl[b * 8 + jt] = p;
    }
}

__global__ __launch_bounds__(64) void final_k(
    const float* __restrict__ Pl, const float* __restrict__ bf,
    float* __restrict__ out)
{
    int t = threadIdx.x;
    if (t < 32) {
        float logit = bf[0];
#pragma unroll
        for (int jt = 0; jt < 8; jt++) logit += Pl[t * 8 + jt];
        out[t] = logit;
        out[32 + t] = 1.f / (1.f + expf(-logit));
    }
}

// ---------------------------------------------------------------------------
extern "C" void kernel_launch(void* const* d_in, const int* in_sizes, int n_in,
                              void* d_out, int out_size, void* d_ws, size_t ws_size,
                              hipStream_t stream)
{
    const int*   inputs = (const int*)  d_in[0];
    const float* emb    = (const float*)d_in[1];
    const float* Wp     = (const float*)d_in[2];
    const float* bp     = (const float*)d_in[3];
    const float* Wo     = (const float*)d_in[4];
    const float* bo     = (const float*)d_in[5];
    const float* ln1_g  = (const float*)d_in[6];
    const float* ln1_b  = (const float*)d_in[7];
    const float* W1     = (const float*)d_in[8];
    const float* b1     = (const float*)d_in[9];
    const float* W2     = (const float*)d_in[10];
    const float* b2     = (const float*)d_in[11];
    const float* ln2_g  = (const float*)d_in[12];
    const float* ln2_b  = (const float*)d_in[13];
    const float* Wh     = (const float*)d_in[14];
    const float* bh     = (const float*)d_in[15];
    const float* Wf     = (const float*)d_in[16];
    const float* bf     = (const float*)d_in[17];
    float* out = (float*)d_out;

    char* p = (char*)d_ws;
    float* X0    = (float*)p;  p += 65536;      // (32,512)
    float* r     = (float*)p;  p += 262144;     // (128,512)
    float* alpha = (float*)p;  p += 1024;       // (128)+pad
    float* Gp    = (float*)p;  p += 8192;       // (32,16,4)
    float* Tpp   = (float*)p;  p += 4194304;    // (32,16,4,512)
    float* C0    = (float*)p;  p += 65536;      // (32,512)
    float* ATT0  = (float*)p;  p += 65536;      // (32,512)
    float* Y1    = (float*)p;  p += 65536;      // (32,512)
    float* Hp1   = (float*)p;  p += 1048576;    // (4,32,2048)
    float* Hp2   = (float*)p;  p += 1048576;    // (16,32,512)
    float* Pl    = (float*)p;  p += 1024;       // (32,8)

    qr_k<<<dim3(32, 4), 256, 0, stream>>>(inputs, emb, Wp, bp, X0, r, alpha);
    xu_k<<<dim3(32, 16), 256, 0, stream>>>(inputs, emb, r, alpha, Tpp, Gp);
    att1_k<<<dim3(32, 8), 256, 0, stream>>>(Tpp, Gp, Wp, bp, C0);
    att2_k<<<dim3(32, 8), 256, 0, stream>>>(C0, Wo, bo, ATT0);
    ln_rows_k<<<32, 256, 0, stream>>>(ATT0, X0, ln1_g, ln1_b, Y1);
    ffn1_k<<<dim3(32, 4), 256, 0, stream>>>(Y1, W1, Hp1);
    ffn2_k<<<dim3(8, 16), 256, 0, stream>>>(Hp1, b1, W2, Hp2);
    headp2_k<<<dim3(32, 8), 256, 0, stream>>>(Hp2, b2, Y1, ln2_g, ln2_b,
                                              Wh, bh, Wf, Pl);
    final_k<<<1, 64, 0, stream>>>(Pl, bf, out);
}

// Round 12
// 198.316 us; speedup vs baseline: 3.1190x; 1.0198x over previous
//
#include <hip/hip_runtime.h>
#include <hip/hip_bf16.h>

// ---------------------------------------------------------------------------
// qr_k: per (b,h): X0row = emb[tok[b,0]] + PE_row0 (sin0=0 even d, cos0=1 odd)
//   q0[f] = X0row . Wq[h][:,f] + bq[f];  alpha[b,h] = q0 . bk[h]
//   r[(b*4+h)][d] = sum_f q0[f] * Wk[h][d][f]
// Grid (32 b, 4 h).  Block (0,0) also zeroes Acc/Cnt for headp3's atomics.
// ---------------------------------------------------------------------------
__global__ __launch_bounds__(256) void qr_k(
    const int* __restrict__ inp, const float* __restrict__ emb,
    const float* __restrict__ Wp, const float* __restrict__ bp,
    float* __restrict__ X0, float* __restrict__ r, float* __restrict__ alpha,
    float* __restrict__ Acc, int* __restrict__ Cnt)
{
    __shared__ float xs[512];
    __shared__ float red[256];
    __shared__ float q0s[128];
    int b = blockIdx.x, h = blockIdx.y, t = threadIdx.x;
    if (b == 0 && h == 0) {
        if (t < 32) Acc[t] = 0.f;
        else if (t < 64) Cnt[t - 32] = 0;
    }
    int tok0 = inp[b * 1024];
#pragma unroll
    for (int rep = 0; rep < 2; rep++) {
        int d = t + rep * 256;
        float v = emb[(long)tok0 * 512 + d] + ((d & 1) ? 1.0f : 0.0f);
        xs[d] = v;
        if (h == 0) X0[b * 512 + d] = v;
    }
    __syncthreads();

    int f = t & 127, dh = t >> 7;
    const float* wq = Wp + (long)h * 196608 + f;
    float acc = 0.f;
#pragma unroll 8
    for (int d = dh * 256; d < dh * 256 + 256; d++)
        acc += xs[d] * wq[(long)d * 384];
    red[t] = acc;
    __syncthreads();
    if (t < 128) q0s[t] = red[t] + red[t + 128] + bp[h * 384 + t];
    __syncthreads();
    if (t < 128) red[t] = q0s[t] * bp[h * 384 + 128 + t];
    __syncthreads();
    for (int w = 64; w >= 1; w >>= 1) {
        if (t < w) red[t] += red[t + w];
        __syncthreads();
    }
    if (t == 0) alpha[b * 4 + h] = red[0];

    const float4* q4 = (const float4*)q0s;
#pragma unroll
    for (int rep = 0; rep < 2; rep++) {
        int d = t + rep * 256;
        const float4* wr = (const float4*)(Wp + ((long)(h * 512 + d)) * 384 + 128);
        float a2 = 0.f;
#pragma unroll 8
        for (int f4 = 0; f4 < 32; f4++) {
            float4 w = wr[f4], qq = q4[f4];
            a2 += w.x * qq.x + w.y * qq.y + w.z * qq.z + w.w * qq.w;
        }
        r[((long)(b * 4 + h)) * 512 + d] = a2;
    }
}

// ---------------------------------------------------------------------------
// xu_k: fused x-gather (PE via native __sinf/__cosf) -> u -> t' partials.
// Grid (32 b, 16 sg), 2 chunks of 32 s per block.
// rs padded to stride 520 (bank-conflict-free, fixed in r11).
// ---------------------------------------------------------------------------
__global__ __launch_bounds__(256) void xu_k(
    const int* __restrict__ inp, const float* __restrict__ emb,
    const float* __restrict__ r, const float* __restrict__ alpha,
    float* __restrict__ Tpp, float* __restrict__ Gp)
{
    __shared__ float xs[32 * 516];     // 66 KB
    __shared__ float rs[4 * 520];      // padded stride
    __shared__ float us[128];          // u[s][h]
    __shared__ int  toks[32];
    int b = blockIdx.x, sg = blockIdx.y, t = threadIdx.x;
    int wave = t >> 6, lane = t & 63;

#pragma unroll
    for (int i = 0; i < 2; i++) {
        int idx = t + i * 256;             // < 512 float4-units
        int h = idx >> 7, k4 = idx & 127;
        *(float4*)&rs[h * 520 + k4 * 4] =
            *(const float4*)&r[((long)(b * 4 + h)) * 512 + k4 * 4];
    }

    float w4[4];
#pragma unroll
    for (int j = 0; j < 4; j++) {
        float expo = (float)(lane * 8 + j * 2) * (1.0f / 512.0f);
        w4[j] = exp2f(-expo * 13.287712379549449f);   // 10000^-expo
    }

    float accT[4][2] = {};
    float gacc = 0.f;
    for (int it = 0; it < 2; it++) {
        int s0 = (sg * 2 + it) * 32;
        __syncthreads();                    // protect xs/us from prev readers
        if (t < 32) toks[t] = inp[b * 1024 + s0 + t];
        __syncthreads();

        // Phase 1: each wave stages 8 rows; x = emb[tok] + PE(s,d) inline
#pragma unroll
        for (int i = 0; i < 8; i++) {
            int row = wave * 8 + i;
            float s = (float)(s0 + row);
            int tok = toks[row];
            const float4* e = (const float4*)&emb[(long)tok * 512 + lane * 8];
            float4 e0 = e[0], e1 = e[1];
            float sv[4], cv[4];
#pragma unroll
            for (int j = 0; j < 4; j++) {
                float ang = s * w4[j];
                sv[j] = __sinf(ang);
                cv[j] = __cosf(ang);
            }
            *(float4*)&xs[row * 516 + lane * 8] =
                make_float4(e0.x + sv[0], e0.y + cv[0], e0.z + sv[1], e0.w + cv[1]);
            *(float4*)&xs[row * 516 + lane * 8 + 4] =
                make_float4(e1.x + sv[2], e1.y + cv[2], e1.z + sv[3], e1.w + cv[3]);
        }
        __syncthreads();

        // Phase 2: u[s,h] = x[s].r[h] + alpha[h]   (thread = (s,h,half))
        {
            int s = t >> 3, h = (t >> 1) & 3, half = t & 1;
            const float* xrow = xs + s * 516 + half * 256;
            const float* rrow = rs + h * 520 + half * 256;
            float acc = 0.f;
#pragma unroll 8
            for (int k = 0; k < 64; k++) {
                float4 xv = *(const float4*)&xrow[k * 4];
                float4 rv = *(const float4*)&rrow[k * 4];
                acc += xv.x * rv.x + xv.y * rv.y + xv.z * rv.z + xv.w * rv.w;
            }
            acc += __shfl_xor(acc, 1);
            if (half == 0) us[s * 4 + h] = acc + alpha[b * 4 + h];
        }
        __syncthreads();

        // gamma partial
        if (t < 4) {
#pragma unroll
            for (int s = 0; s < 32; s++) gacc += us[s * 4 + t];
        }

        // Phase 3: t' partials, d = t and t+256
#pragma unroll 4
        for (int s = 0; s < 32; s++) {
            float x0 = xs[s * 516 + t];
            float x1 = xs[s * 516 + 256 + t];
#pragma unroll
            for (int h = 0; h < 4; h++) {
                float uv = us[s * 4 + h];
                accT[h][0] += uv * x0;
                accT[h][1] += uv * x1;
            }
        }
    }
    long base = (long)(b * 16 + sg) * 2048;
#pragma unroll
    for (int h = 0; h < 4; h++) {
        Tpp[base + h * 512 + t] = accT[h][0];
        Tpp[base + h * 512 + 256 + t] = accT[h][1];
    }
    if (t < 4) Gp[(b * 16 + sg) * 4 + t] = gacc;
}

// ---------------------------------------------------------------------------
// att1_k: c0[b,h*128+e] = scale*(sum_d t'[h][d] Wv[h][d][e] + gamma[h] bv)
// Grid (32 b, 8 jt). Sums 16 sg-partials of t' and gamma on load.
// ---------------------------------------------------------------------------
__global__ __launch_bounds__(256) void att1_k(
    const float* __restrict__ Tpp, const float* __restrict__ Gp,
    const float* __restrict__ Wp, const float* __restrict__ bp,
    float* __restrict__ C0)
{
    __shared__ float tps[512];
    __shared__ float red[256];
    int b = blockIdx.x, jt = blockIdx.y, t = threadIdx.x;
    int h = jt >> 1, e0 = (jt & 1) * 64;
#pragma unroll
    for (int i = 0; i < 2; i++) {
        int d = t + i * 256;
        float v = 0.f;
#pragma unroll 8
        for (int sg = 0; sg < 16; sg++)
            v += Tpp[(long)b * 32768 + sg * 2048 + h * 512 + d];
        tps[d] = v;
    }
    __syncthreads();
    int e = e0 + (t & 63), rg = t >> 6;
    const float* wv = Wp + (long)h * 196608 + 256 + e;
    float acc = 0.f;
#pragma unroll 8
    for (int d = rg * 128; d < rg * 128 + 128; d++)
        acc += tps[d] * wv[(long)d * 384];
    red[t] = acc;
    __syncthreads();
    if (t < 64) {
        float gam = 0.f;
#pragma unroll
        for (int sg = 0; sg < 16; sg++) gam += Gp[(b * 16 + sg) * 4 + h];
        float sum = red[t] + red[t + 64] + red[t + 128] + red[t + 192];
        float c = 0.03125f * (sum + gam * bp[h * 384 + 256 + e0 + t]);
        C0[b * 512 + h * 128 + e0 + t] = c;
    }
}

// ---------------------------------------------------------------------------
// att2s_k: A1 = C0 @ Wo + bo + X0 (pre-LN1 activations) and per-(b,jt)
//   LN stats (sum, sumsq over its 64 cols).  Grid (32 b, 8 jt).
// ---------------------------------------------------------------------------
__global__ __launch_bounds__(256) void att2s_k(
    const float* __restrict__ C0, const float* __restrict__ Wo,
    const float* __restrict__ bo, const float* __restrict__ X0,
    float* __restrict__ A1, float* __restrict__ Stat)
{
    __shared__ float c0s[512];
    __shared__ float red[256];
    int b = blockIdx.x, jt = blockIdx.y, t = threadIdx.x;
    c0s[t] = C0[b * 512 + t];
    c0s[t + 256] = C0[b * 512 + t + 256];
    __syncthreads();
    int j = jt * 64 + (t & 63), rg = t >> 6;
    float acc = 0.f;
#pragma unroll 8
    for (int d = rg * 128; d < rg * 128 + 128; d++)
        acc += c0s[d] * Wo[(long)d * 512 + j];
    red[t] = acc;
    __syncthreads();
    if (t < 64) {
        int jj = jt * 64 + t;
        float a = red[t] + red[t + 64] + red[t + 128] + red[t + 192]
                + bo[jj] + X0[b * 512 + jj];
        A1[b * 512 + jj] = a;
        float s = a, q = a * a;
#pragma unroll
        for (int off = 32; off; off >>= 1) {
            s += __shfl_down(s, off);
            q += __shfl_down(q, off);
        }
        if (t == 0) {
            Stat[(b * 8 + jt) * 2]     = s;
            Stat[(b * 8 + jt) * 2 + 1] = q;
        }
    }
}

// ---------------------------------------------------------------------------
// ffn1_k: LN1-on-load + Hp1[ks][32][2048] = Y1[:, kchunk] @ W1[kchunk, :]
// Grid (32 jt, 4 ks). Y1 = (A1 - mean)*rstd*g1 + b1v from Stat partials.
// ---------------------------------------------------------------------------
__global__ __launch_bounds__(256) void ffn1_k(
    const float* __restrict__ A1, const float* __restrict__ Stat,
    const float* __restrict__ g1, const float* __restrict__ b1v,
    const float* __restrict__ W1, float* __restrict__ Hp1)
{
    __shared__ float at[32][128];
    __shared__ float mrs[32][2];
    int jt = blockIdx.x, ks = blockIdx.y, t = threadIdx.x;
    if (t < 32) {
        float s = 0.f, q = 0.f;
#pragma unroll
        for (int p8 = 0; p8 < 8; p8++) {
            s += Stat[(t * 8 + p8) * 2];
            q += Stat[(t * 8 + p8) * 2 + 1];
        }
        float mean = s * (1.0f / 512.0f);
        float var = q * (1.0f / 512.0f) - mean * mean;
        mrs[t][0] = mean;
        mrs[t][1] = rsqrtf(var + 0.001f);
    }
    __syncthreads();
#pragma unroll
    for (int i = 0; i < 4; i++) {
        int idx = t + i * 256;
        int row = idx >> 5, f4 = idx & 31;
        int col = ks * 128 + f4 * 4;
        float4 a4 = *(const float4*)&A1[(long)row * 512 + col];
        float4 g4 = *(const float4*)&g1[col];
        float4 bb = *(const float4*)&b1v[col];
        float mean = mrs[row][0], rstd = mrs[row][1];
        float4 v;
        v.x = (a4.x - mean) * rstd * g4.x + bb.x;
        v.y = (a4.y - mean) * rstd * g4.y + bb.y;
        v.z = (a4.z - mean) * rstd * g4.z + bb.z;
        v.w = (a4.w - mean) * rstd * g4.w + bb.w;
        ((float4*)at)[idx] = v;
    }
    __syncthreads();
    int j = jt * 64 + (t & 63), rg = t >> 6;
    float acc[8] = {};
    const float* wp = W1 + (long)(ks * 128) * 2048 + j;
#pragma unroll 4
    for (int k = 0; k < 128; k++) {
        float wv = wp[(long)k * 2048];
#pragma unroll
        for (int rr = 0; rr < 8; rr++)
            acc[rr] += at[rg * 8 + rr][k] * wv;
    }
#pragma unroll
    for (int rr = 0; rr < 8; rr++)
        Hp1[((long)(ks * 32 + rg * 8 + rr)) * 2048 + j] = acc[rr];
}

// ---------------------------------------------------------------------------
// FFN2 partials, fused H1 = relu(sum_ks Hp1 + b1) at staging.
// Grid (8 jt, 16 ks).
// ---------------------------------------------------------------------------
__global__ __launch_bounds__(256) void ffn2_k(
    const float* __restrict__ Hp1, const float* __restrict__ b1,
    const float* __restrict__ W2, float* __restrict__ Hp2)
{
    __shared__ float at[32][128];
    int jt = blockIdx.x, ks = blockIdx.y, t = threadIdx.x;
#pragma unroll
    for (int i = 0; i < 4; i++) {
        int idx = t + i * 256;
        int row = idx >> 5, f4 = idx & 31;
        int col4 = ks * 32 + f4;
        float4 v = ((const float4*)b1)[col4];
#pragma unroll
        for (int p = 0; p < 4; p++) {
            float4 pv = ((const float4*)Hp1)[(long)p * 16384 + (long)row * 512 + col4];
            v.x += pv.x; v.y += pv.y; v.z += pv.z; v.w += pv.w;
        }
        v.x = fmaxf(v.x, 0.f); v.y = fmaxf(v.y, 0.f);
        v.z = fmaxf(v.z, 0.f); v.w = fmaxf(v.w, 0.f);
        ((float4*)at)[idx] = v;
    }
    __syncthreads();
    int j = jt * 64 + (t & 63), rg = t >> 6;
    float acc[8] = {};
    const float* wp = W2 + (long)(ks * 128) * 512 + j;
#pragma unroll 4
    for (int k = 0; k < 128; k++) {
        float wv = wp[(long)k * 512];
#pragma unroll
        for (int rr = 0; rr < 8; rr++)
            acc[rr] += at[rg * 8 + rr][k] * wv;
    }
#pragma unroll
    for (int rr = 0; rr < 8; rr++)
        Hp2[((long)(ks * 32 + rg * 8 + rr)) * 512 + j] = acc[rr];
}

// ---------------------------------------------------------------------------
// headp3_k: Y1 recompute (LN1 from A1+Stat) + LN2 + head partial + atomic
//   finish (8th arriver per b computes logit+sigmoid, writes out).
// Grid (32 b, 8 jt).
// ---------------------------------------------------------------------------
__global__ __launch_bounds__(256) void headp3_k(
    const float* __restrict__ Hp2, const float* __restrict__ b2,
    const float* __restrict__ A1, const float* __restrict__ Stat,
    const float* __restrict__ g1v, const float* __restrict__ b1v,
    const float* __restrict__ g2v, const float* __restrict__ b2v,
    const float* __restrict__ Wh, const float* __restrict__ bh,
    const float* __restrict__ Wf, const float* __restrict__ bf,
    float* __restrict__ Acc, int* __restrict__ Cnt, float* __restrict__ out)
{
    __shared__ float xs[512];
    __shared__ float red[256];
    __shared__ float sd[8];
    __shared__ float mr[2];
    int b = blockIdx.x, jt = blockIdx.y, t = threadIdx.x;
    if (t == 0) {
        float s = 0.f, q = 0.f;
#pragma unroll
        for (int p8 = 0; p8 < 8; p8++) {
            s += Stat[(b * 8 + p8) * 2];
            q += Stat[(b * 8 + p8) * 2 + 1];
        }
        float mean = s * (1.0f / 512.0f);
        mr[0] = mean;
        mr[1] = rsqrtf(q * (1.0f / 512.0f) - mean * mean + 0.001f);
    }
    __syncthreads();
    float mean1 = mr[0], rstd1 = mr[1];
    float a[2];
#pragma unroll
    for (int rep = 0; rep < 2; rep++) {
        int j = t + rep * 256;
        float y1 = (A1[b * 512 + j] - mean1) * rstd1 * g1v[j] + b1v[j];
        float v = b2[j] + y1;
#pragma unroll
        for (int ks = 0; ks < 16; ks++)
            v += Hp2[((long)(ks * 32 + b)) * 512 + j];
        a[rep] = v;
    }
    float s = a[0] + a[1];
#pragma unroll
    for (int off = 32; off; off >>= 1) s += __shfl_down(s, off);
    if ((t & 63) == 0) sd[t >> 6] = s;
    __syncthreads();
    float mean = (sd[0] + sd[1] + sd[2] + sd[3]) * (1.0f / 512.0f);
    float d0 = a[0] - mean, d1 = a[1] - mean;
    float v2 = d0 * d0 + d1 * d1;
#pragma unroll
    for (int off = 32; off; off >>= 1) v2 += __shfl_down(v2, off);
    if ((t & 63) == 0) sd[4 + (t >> 6)] = v2;
    __syncthreads();
    float var = (sd[4] + sd[5] + sd[6] + sd[7]) * (1.0f / 512.0f);
    float rstd = rsqrtf(var + 0.001f);
    xs[t] = d0 * rstd * g2v[t] + b2v[t];
    xs[t + 256] = d1 * rstd * g2v[t + 256] + b2v[t + 256];
    __syncthreads();

    int j = jt * 64 + (t & 63), rg = t >> 6;
    const float* w = Wh + j;
    float acc = 0.f;
#pragma unroll 8
    for (int d = rg * 128; d < rg * 128 + 128; d++)
        acc += xs[d] * w[(long)d * 512];
    red[t] = acc;
    __syncthreads();
    if (t < 64) {
        int jj = jt * 64 + t;
        float hid = red[t] + red[t + 64] + red[t + 128] + red[t + 192] + bh[jj];
        hid = fmaxf(hid, 0.f);
        float p = hid * Wf[jj];
#pragma unroll
        for (int off = 32; off; off >>= 1) p += __shfl_down(p, off);
        if (t == 0) {
            atomicAdd(&Acc[b], p);
            __threadfence();
            int old = atomicAdd(&Cnt[b], 1);
            if (old == 7) {
                float tot = atomicAdd(&Acc[b], 0.0f);
                float logit = tot + bf[0];
                out[b] = logit;
                out[32 + b] = 1.f / (1.f + expf(-logit));
            }
        }
    }
}

// ---------------------------------------------------------------------------
extern "C" void kernel_launch(void* const* d_in, const int* in_sizes, int n_in,
                              void* d_out, int out_size, void* d_ws, size_t ws_size,
                              hipStream_t stream)
{
    const int*   inputs = (const int*)  d_in[0];
    const float* emb    = (const float*)d_in[1];
    const float* Wp     = (const float*)d_in[2];
    const float* bp     = (const float*)d_in[3];
    const float* Wo     = (const float*)d_in[4];
    const float* bo     = (const float*)d_in[5];
    const float* ln1_g  = (const float*)d_in[6];
    const float* ln1_b  = (const float*)d_in[7];
    const float* W1     = (const float*)d_in[8];
    const float* b1     = (const float*)d_in[9];
    const float* W2     = (const float*)d_in[10];
    const float* b2     = (const float*)d_in[11];
    const float* ln2_g  = (const float*)d_in[12];
    const float* ln2_b  = (const float*)d_in[13];
    const float* Wh     = (const float*)d_in[14];
    const float* bh     = (const float*)d_in[15];
    const float* Wf     = (const float*)d_in[16];
    const float* bf     = (const float*)d_in[17];
    float* out = (float*)d_out;

    char* p = (char*)d_ws;
    float* X0    = (float*)p;  p += 65536;      // (32,512)
    float* r     = (float*)p;  p += 262144;     // (128,512)
    float* alpha = (float*)p;  p += 1024;       // (128)+pad
    float* Gp    = (float*)p;  p += 8192;       // (32,16,4)
    float* Tpp   = (float*)p;  p += 4194304;    // (32,16,4,512)
    float* C0    = (float*)p;  p += 65536;      // (32,512)
    float* A1    = (float*)p;  p += 65536;      // (32,512)  pre-LN1
    float* Stat  = (float*)p;  p += 2048;       // (32,8,2)
    float* Acc   = (float*)p;  p += 512;        // (32)+pad
    int*   Cnt   = (int*)p;    p += 512;        // (32)+pad
    float* Hp1   = (float*)p;  p += 1048576;    // (4,32,2048)
    float* Hp2   = (float*)p;  p += 1048576;    // (16,32,512)

    qr_k<<<dim3(32, 4), 256, 0, stream>>>(inputs, emb, Wp, bp, X0, r, alpha,
                                          Acc, Cnt);
    xu_k<<<dim3(32, 16), 256, 0, stream>>>(inputs, emb, r, alpha, Tpp, Gp);
    att1_k<<<dim3(32, 8), 256, 0, stream>>>(Tpp, Gp, Wp, bp, C0);
    att2s_k<<<dim3(32, 8), 256, 0, stream>>>(C0, Wo, bo, X0, A1, Stat);
    ffn1_k<<<dim3(32, 4), 256, 0, stream>>>(A1, Stat, ln1_g, ln1_b, W1, Hp1);
    ffn2_k<<<dim3(8, 16), 256, 0, stream>>>(Hp1, b1, W2, Hp2);
    headp3_k<<<dim3(32, 8), 256, 0, stream>>>(Hp2, b2, A1, Stat,
                                              ln1_g, ln1_b, ln2_g, ln2_b,
                                              Wh, bh, Wf, bf, Acc, Cnt, out);
}